// Round 5
// baseline (1722.106 us; speedup 1.0000x reference)
//
#include <hip/hip_runtime.h>
#include <math.h>

#define MC      50000
#define MPATHS  100000
#define NSTEPS  180
#define NOPTS   32

typedef __attribute__((ext_vector_type(8))) short short8;
typedef __attribute__((ext_vector_type(4))) float float4v;
typedef _Float16 half2v __attribute__((ext_vector_type(2)));
typedef unsigned u32x32 __attribute__((ext_vector_type(32)));

// ---------- helpers ----------
static __device__ __forceinline__ unsigned bf16u(float x) {        // RNE
    unsigned u = __float_as_uint(x);
    return (u + 0x7fffu + ((u >> 16) & 1u)) >> 16;
}
static __device__ __forceinline__ float bf16val(float x) {
    return __uint_as_float(bf16u(x) << 16);
}
static __device__ __forceinline__ unsigned pkh2(float a, float b) { // f16 pair (fallback path)
    half2v h; h.x = (_Float16)a; h.y = (_Float16)b;
    return __builtin_bit_cast(unsigned, h);
}
static __device__ __forceinline__ unsigned pkrtz(float a, float b) {
    auto h = __builtin_amdgcn_cvt_pkrtz(a, b);
    return __builtin_bit_cast(unsigned, h);
}
static __device__ __forceinline__ float fdot2(unsigned w, unsigned h, float c) {
    return __builtin_amdgcn_fdot2(__builtin_bit_cast(half2v, w),
                                  __builtin_bit_cast(half2v, h), c, false);
}
static __device__ __forceinline__ short8 fr4(unsigned a, unsigned b,
                                             unsigned c, unsigned d) {
    union { unsigned u[4]; short8 s; } t;
    t.u[0] = a; t.u[1] = b; t.u[2] = c; t.u[3] = d;
    return t.s;
}
static __device__ __forceinline__ float4v mfma16(short8 a, short8 b, float4v c) {
    return __builtin_amdgcn_mfma_f32_16x16x32_bf16(a, b, c, 0, 0, 0);
}

// ws table region (ints): [0..511]=mA  [512..1023]=kA(kid->rank)
//                          [1024..1535]=nB  [1536..2047]=kB(kid->rank)
//                          [2048..2079]=Minv (k-rank -> W2 local column, fast path)

// ---------- probe 1: m-map (A) and n-map (B); trusts only C/D layout ----------
__global__ void probe_mn(int* tbl) {
    const int lane = threadIdx.x;
    for (int s = lane; s < 2048; s += 64) tbl[s] = 0;   // defaults (safe clamp later)
    const float4v z4 = {0.f, 0.f, 0.f, 0.f};
    for (int L = 0; L < 64; ++L)
        for (int j = 0; j < 8; ++j) {
            unsigned au[4] = {0u, 0u, 0u, 0u};
            if (lane == L) au[j >> 1] = 0x3F80u << (16 * (j & 1));
            short8 a = fr4(au[0], au[1], au[2], au[3]);
            short8 b = fr4(0x3F803F80u, 0x3F803F80u, 0x3F803F80u, 0x3F803F80u);
            float4v d = mfma16(a, b, z4);
            if ((lane & 15) == 0) {
                #pragma unroll
                for (int r = 0; r < 4; ++r)
                    if (d[r] != 0.0f) tbl[L * 8 + j] = (lane >> 4) * 4 + r;
            }
        }
    for (int L = 0; L < 64; ++L)
        for (int j = 0; j < 8; ++j) {
            unsigned bu[4] = {0u, 0u, 0u, 0u};
            if (lane == L) bu[j >> 1] = 0x3F80u << (16 * (j & 1));
            short8 a = fr4(0x3F803F80u, 0x3F803F80u, 0x3F803F80u, 0x3F803F80u);
            short8 b = fr4(bu[0], bu[1], bu[2], bu[3]);
            float4v d = mfma16(a, b, z4);
            if ((lane >> 4) == 0 && d[0] != 0.0f) tbl[1024 + L * 8 + j] = (lane & 15);
        }
}

// ---------- probe 2: k-equivalence classes between A-slots and B-slots ----------
__global__ void probe_k(int* tbl) {
    const int lane = threadIdx.x;
    const int sA = blockIdx.x;              // 0..511
    const float4v z4 = {0.f, 0.f, 0.f, 0.f};
    unsigned au[4] = {0u, 0u, 0u, 0u};
    if (lane == (sA >> 3)) au[(sA & 7) >> 1] = 0x3F80u << (16 * (sA & 1));
    short8 a = fr4(au[0], au[1], au[2], au[3]);
    int kid = -1;
    for (int sB = 0; sB < 512; ++sB) {
        unsigned bu[4] = {0u, 0u, 0u, 0u};
        const int LB = sB >> 3, jB = sB & 7;
        if (lane == LB) bu[jB >> 1] = 0x3F80u << (16 * (jB & 1));
        short8 b = fr4(bu[0], bu[1], bu[2], bu[3]);
        float4v d = mfma16(a, b, z4);
        bool hit = (d[0] != 0.f) | (d[1] != 0.f) | (d[2] != 0.f) | (d[3] != 0.f);
        if (__any(hit)) {
            if (kid < 0) kid = sB;
            if (lane == 0) tbl[1536 + sB] = kid;   // benign same-value races
        }
    }
    if (lane == 0) tbl[512 + sA] = (kid < 0) ? 0 : kid;
}

// ---------- probe 3: rank k-classes; verify layout stack + fast-path conditions ----------
// Fast path additionally requires (checked exactly):
//   (a) B n-map standard: nb(lane,j) == lane&15
//   (b) B k-ranks independent of lane&15 (function of (g=lane>>4, j) only)
//   (c) (g,j) -> rank bijective onto 0..31
// Then Minv[rank(g,j)] = 16*((j>>2)&1) + 4*g + 2*((j>>1)&1) + (j&1) re-indexes W2
// columns so layer-2's B fragment equals layer-1's packed D registers verbatim.
__global__ void finalize_verify(int* tbl, int* flag) {
    __shared__ int cnt[32];
    __shared__ int minv[32];
    const int lane = threadIdx.x;
    if (lane < 32) { cnt[lane] = 0; minv[lane] = 0; }
    int rA[8], rB[8];
    #pragma unroll
    for (int j = 0; j < 8; ++j) {
        const int s = lane * 8 + j;
        const int kidA = tbl[512 + s], kidB = tbl[1536 + s];
        int ra = 0, rb = 0;
        for (int u = 0; u < 512; ++u) {
            const int canon = (tbl[1536 + u] == u);
            ra += canon & (u < kidA);
            rb += canon & (u < kidB);
        }
        rA[j] = ra & 31; rB[j] = rb & 31;
    }
    __syncthreads();
    #pragma unroll
    for (int j = 0; j < 8; ++j) {
        tbl[512 + lane * 8 + j]  = rA[j];
        tbl[1536 + lane * 8 + j] = rB[j];
    }
    // verify: integer GEMM through discovered tables, exact compare
    unsigned au[4] = {0u, 0u, 0u, 0u}, bu[4] = {0u, 0u, 0u, 0u};
    #pragma unroll
    for (int j = 0; j < 8; ++j) {
        const int s = lane * 8 + j;
        const int m = tbl[s] & 15, ka = rA[j];
        const int n = tbl[1024 + s] & 15, kb = rB[j];
        const int fv = ((m * 7 + ka * 3) % 5) - 2;
        const int gv = ((kb * 5 + n * 11) % 7) - 3;
        au[j >> 1] |= bf16u((float)fv) << (16 * (j & 1));
        bu[j >> 1] |= bf16u((float)gv) << (16 * (j & 1));
    }
    const float4v z4 = {0.f, 0.f, 0.f, 0.f};
    float4v d = mfma16(fr4(au[0], au[1], au[2], au[3]),
                       fr4(bu[0], bu[1], bu[2], bu[3]), z4);
    const int col = lane & 15;
    bool ok = true;
    #pragma unroll
    for (int r = 0; r < 4; ++r) {
        const int row = (lane >> 4) * 4 + r;
        int ref = 0;
        for (int k = 0; k < 32; ++k)
            ref += (((row * 7 + k * 3) % 5) - 2) * (((k * 5 + col * 11) % 7) - 3);
        ok = ok && (d[r] == (float)ref);
    }
    // fast-path conditions (a),(b)
    bool okf = ok;
    #pragma unroll
    for (int j = 0; j < 8; ++j) {
        okf = okf && ((tbl[1024 + lane * 8 + j] & 15) == (lane & 15));
        const int ref = __shfl(rB[j], lane & 48, 64);
        okf = okf && (rB[j] == ref);
    }
    // (c) bijectivity + Minv build (c==0 lanes cover all 32 (g,j) positions)
    if ((lane & 15) == 0) {
        const int g = lane >> 4;
        #pragma unroll
        for (int j = 0; j < 8; ++j) {
            atomicAdd(&cnt[rB[j]], 1);
            minv[rB[j]] = 16 * ((j >> 2) & 1) + 4 * g + 2 * ((j >> 1) & 1) + (j & 1);
        }
    }
    __syncthreads();
    if (lane < 32) {
        okf = okf && (cnt[lane] == 1);
        tbl[2048 + lane] = minv[lane];
    }
    const bool allok = __all(okf);
    if (lane == 0) *flag = allok ? 1 : 0;
}

// ---------- build W1/W2 A-fragment tables (after verify tables final) ----------
// W2 columns permuted by Minv so layer-2 B-frag == layer-1 packed D registers.
__global__ void build_frags(const float* __restrict__ W1, const float* __restrict__ b1,
                            const float* __restrict__ W2, const int* __restrict__ tbl,
                            uint4* __restrict__ w1f, uint4* __restrict__ w2f) {
    const int t = blockIdx.x * 256 + threadIdx.x;   // 0..3071
    if (t >= 3072) return;
    const int lane = t & 63, frag = t >> 6;
    const float rateB = bf16val(0.025f);
    unsigned u[4] = {0u, 0u, 0u, 0u};
    if (frag < 16) {            // W1: net=frag>>2, mt=frag&3 ; k 0..5 hi, 6..11 lo-residual
        const int net = frag >> 2, mt = frag & 3;
        #pragma unroll
        for (int j = 0; j < 8; ++j) {
            const int s = lane * 8 + j;
            const int m = tbl[s] & 15, k = tbl[512 + s] & 31;
            unsigned bits = 0u;
            if (k < 12) {
                const int kk = (k < 6) ? k : k - 6;
                const int M = net * 64 + 16 * mt + m;
                float v;
                if (kk == 0)                 v = W1[M * 4 + 0];
                else if (kk == 1 || kk == 4) v = W1[M * 4 + 1];
                else if (kk == 2 || kk == 5) v = W1[M * 4 + 2];
                else                         v = W1[M * 4 + 3] + b1[M] / rateB;
                bits = (k < 6) ? bf16u(v) : bf16u(v - bf16val(v));
            }
            u[j >> 1] |= bits << (16 * (j & 1));
        }
        w1f[frag * 64 + lane] = make_uint4(u[0], u[1], u[2], u[3]);
    } else {                    // W2: f2=frag-16: net=f2>>3, mt=(f2>>1)&3, kc=f2&1
        const int f2 = frag - 16;
        const int net = f2 >> 3, mt = (f2 >> 1) & 3, kc = f2 & 1;
        #pragma unroll
        for (int j = 0; j < 8; ++j) {
            const int s = lane * 8 + j;
            const int m = tbl[s] & 15, k = tbl[512 + s] & 31;
            const float v = W2[(net * 64 + 16 * mt + m) * 64 + 32 * kc + tbl[2048 + k]];
            u[j >> 1] |= bf16u(v) << (16 * (j & 1));
        }
        w2f[f2 * 64 + lane] = make_uint4(u[0], u[1], u[2], u[3]);
    }
}

// ---------- main MFMA path-sim: 4 waves/block, 1 net/wave, 2 path-groups/block ----------
// Each block owns 128 paths (A = lanes, B = lanes+64). Every wave computes its net
// for BOTH groups per step: two independent dependency chains per wave (2x ILP),
// barrier/exchange amortized over 2x work. B1 operands assembled in-register via
// ds_bpermute + per-lane v_perm selectors (discovered tables); layer-2 B fragment
// = layer-1 packed D registers verbatim (Minv-permuted W2). No spill at (256,3).
__global__ __launch_bounds__(256, 3)
void sde_mfma_w4(const float* __restrict__ x, const float* __restrict__ z,
                 const float* __restrict__ z1, const float* __restrict__ b2,
                 const float* __restrict__ Wo, const float* __restrict__ bo,
                 const int* __restrict__ tbl, const uint4* __restrict__ w1f,
                 const uint4* __restrict__ w2f, const int* __restrict__ flag,
                 float* __restrict__ acc)
{
    if (*flag != 1) return;
    __shared__ __align__(16) float wo_s[256];
    __shared__ __align__(16) float b2_s[256];
    __shared__ float dxch[2][4][128];
    __shared__ float ls_k[NOPTS];
    __shared__ int   maskTab[NSTEPS + 4];

    const int tid = threadIdx.x;
    const int wv = tid >> 6, lane = tid & 63;   // wv == net index
    const int q = lane >> 4, c = lane & 15;

    for (int j = tid; j < 256; j += 256) { wo_s[j] = Wo[j]; b2_s[j] = b2[j]; }
    for (int j = tid; j < NSTEPS + 4; j += 256) maskTab[j] = 0;
    if (tid < NOPTS) ls_k[tid] = x[2 * tid + 1];
    __syncthreads();
    if (tid < NOPTS) atomicOr(&maskTab[(int)x[2 * tid]], 1 << tid);
    __syncthreads();

    // per-lane B1 assembly tables from discovered k-map
    // rows: 0=t 1=S 2=V 3=rate 4=Sres 5=Vres 6=zero
    const unsigned rate16 = bf16u(0.025f);
    unsigned selAB[4], dynM[4], cU[4], mT[4];
    {
        int rowj[8];
        #pragma unroll
        for (int j = 0; j < 8; ++j) {
            const int kb = tbl[1536 + lane * 8 + j] & 31;
            rowj[j] = (kb < 6) ? kb : ((kb < 12) ? kb - 6 : 6);
        }
        #pragma unroll
        for (int w = 0; w < 4; ++w) {
            unsigned s = 0, d = 0, cu = 0, mt_ = 0;
            #pragma unroll
            for (int h = 0; h < 2; ++h) {
                const int r = rowj[2 * w + h];
                unsigned hs = 0x0504u, hd = 0u, hcu = 0u, hmt = 0u;
                if      (r == 1) { hs = 0x0504u; hd = 0xFFFFu; }   // S  = Ap lo16
                else if (r == 2) { hs = 0x0706u; hd = 0xFFFFu; }   // V  = Ap hi16
                else if (r == 4) { hs = 0x0100u; hd = 0xFFFFu; }   // Sr = Bp lo16
                else if (r == 5) { hs = 0x0302u; hd = 0xFFFFu; }   // Vr = Bp hi16
                else if (r == 0) { hmt = 0xFFFFu; }                // t (per-step)
                else if (r == 3) { hcu = rate16; }                 // rate const
                // r==6: zero
                s  |= hs  << (16 * h); d   |= hd  << (16 * h);
                cu |= hcu << (16 * h); mt_ |= hmt << (16 * h);
            }
            selAB[w] = s; dynM[w] = d; cU[w] = cu; mT[w] = mt_;
        }
    }

    // two path groups per block
    const int pA_ = blockIdx.x * 128 + lane;
    const int pB_ = pA_ + 64;
    const float wgtA = (pA_ < MPATHS) ? 1.0f : 0.0f;
    const float wgtB = (pB_ < MPATHS) ? 1.0f : 0.0f;
    int pcA = (pA_ < MPATHS) ? pA_ : (MPATHS - 1);
    int pcB = (pB_ < MPATHS) ? pB_ : (MPATHS - 1);
    float sgnA = 1.0f, sgnB = 1.0f; int rwA = pcA, rwB = pcB;
    if (pcA >= MC) { sgnA = -1.0f; rwA -= MC; }
    if (pcB >= MC) { sgnB = -1.0f; rwB -= MC; }
    const float* __restrict__ zrA  = z  + (size_t)rwA * NSTEPS;
    const float* __restrict__ z1rA = z1 + (size_t)rwA * NSTEPS;
    const float* __restrict__ zrB  = z  + (size_t)rwB * NSTEPS;
    const float* __restrict__ z1rB = z1 + (size_t)rwB * NSTEPS;

    const float hh = 1.0f / 360.0f, sqh = sqrtf(hh);
    const float s75 = 0.86602540378443864676f;
    const float bon = bo[wv];

    // hoisted A fragments for this wave's net (held in VGPRs across all steps)
    uint4 a1f[4], a2f[8];
    #pragma unroll
    for (int mt = 0; mt < 4; ++mt) {
        a1f[mt]         = w1f[(wv * 4 + mt) * 64 + lane];
        a2f[2 * mt]     = w2f[((wv * 4 + mt) * 2 + 0) * 64 + lane];
        a2f[2 * mt + 1] = w2f[((wv * 4 + mt) * 2 + 1) * 64 + lane];
    }

    float SA = 100.0f, VA = 0.04f, SB = 100.0f, VB = 0.04f;

    #pragma unroll 1
    for (int i = 0; i < NSTEPS; ++i) {
        // per-wave multiplier of this net's output, for both groups
        float multA, multB;
        if (wv == 1) {
            multA = sqh * (sgnA * zrA[i]);
            multB = sqh * (sgnB * zrB[i]);
        } else if (wv == 3) {
            multA = sqh * (sgnA * (-0.5f * zrA[i] + s75 * z1rA[i]));
            multB = sqh * (sgnB * (-0.5f * zrB[i] + s75 * z1rB[i]));
        } else {
            multA = hh; multB = hh;
        }

        const float t = (float)i * hh;
        const unsigned tB = bf16u(t);
        const unsigned tB2 = tB | (tB << 16);
        unsigned UW[4];
        #pragma unroll
        for (int w = 0; w < 4; ++w) UW[w] = cU[w] | (mT[w] & tB2);

        // per-lane packed state words (own path), both groups
        const unsigned ShuA = bf16u(SA), VhuA = bf16u(VA);
        const unsigned PAA = ShuA | (VhuA << 16);
        const float SrA = SA - __uint_as_float(ShuA << 16);
        const float VrA = VA - __uint_as_float(VhuA << 16);
        const unsigned PBA = __builtin_amdgcn_perm(__float_as_uint(VrA),
                                                   __float_as_uint(SrA), 0x07060302u);
        const unsigned ShuB = bf16u(SB), VhuB = bf16u(VB);
        const unsigned PAB = ShuB | (VhuB << 16);
        const float SrB = SB - __uint_as_float(ShuB << 16);
        const float VrB = VB - __uint_as_float(VhuB << 16);
        const unsigned PBB = __builtin_amdgcn_perm(__float_as_uint(VrB),
                                                   __float_as_uint(SrB), 0x07060302u);

        float part[2][4] = {{0.f, 0.f, 0.f, 0.f}, {0.f, 0.f, 0.f, 0.f}};
        const float4v z4 = {0.f, 0.f, 0.f, 0.f};

        #pragma unroll
        for (int nt = 0; nt < 4; ++nt) {
            const int a = (nt << 6) | (c << 2);
            // B1 for both groups (independent chains)
            const unsigned ApA = (unsigned)__builtin_amdgcn_ds_bpermute(a, (int)PAA);
            const unsigned BpA = (unsigned)__builtin_amdgcn_ds_bpermute(a, (int)PBA);
            const unsigned ApB = (unsigned)__builtin_amdgcn_ds_bpermute(a, (int)PAB);
            const unsigned BpB = (unsigned)__builtin_amdgcn_ds_bpermute(a, (int)PBB);
            unsigned B1A[4], B1B[4];
            #pragma unroll
            for (int w = 0; w < 4; ++w) {
                B1A[w] = (__builtin_amdgcn_perm(ApA, BpA, selAB[w]) & dynM[w]) | UW[w];
                B1B[w] = (__builtin_amdgcn_perm(ApB, BpB, selAB[w]) & dynM[w]) | UW[w];
            }
            // layer 1 MFMA -> relu -> bf16 perm-pack (registers only), both groups
            unsigned pkA0[4], pkA1[4], pkB0[4], pkB1[4];
            #pragma unroll
            for (int mt = 0; mt < 4; ++mt) {
                const short8 A1 = fr4(a1f[mt].x, a1f[mt].y, a1f[mt].z, a1f[mt].w);
                float4v dA = mfma16(A1, fr4(B1A[0], B1A[1], B1A[2], B1A[3]), z4);
                float4v dB = mfma16(A1, fr4(B1B[0], B1B[1], B1B[2], B1B[3]), z4);
                const unsigned a0 = __float_as_uint(fmaxf(dA[0], 0.f));
                const unsigned a1 = __float_as_uint(fmaxf(dA[1], 0.f));
                const unsigned a2 = __float_as_uint(fmaxf(dA[2], 0.f));
                const unsigned a3 = __float_as_uint(fmaxf(dA[3], 0.f));
                pkA0[mt] = __builtin_amdgcn_perm(a1, a0, 0x07060302u);
                pkA1[mt] = __builtin_amdgcn_perm(a3, a2, 0x07060302u);
                const unsigned b0 = __float_as_uint(fmaxf(dB[0], 0.f));
                const unsigned b1_ = __float_as_uint(fmaxf(dB[1], 0.f));
                const unsigned b2_ = __float_as_uint(fmaxf(dB[2], 0.f));
                const unsigned b3 = __float_as_uint(fmaxf(dB[3], 0.f));
                pkB0[mt] = __builtin_amdgcn_perm(b1_, b0, 0x07060302u);
                pkB1[mt] = __builtin_amdgcn_perm(b3, b2_, 0x07060302u);
            }
            // layer-2 B fragments are the packed registers verbatim
            const short8 BkA0 = fr4(pkA0[0], pkA1[0], pkA0[1], pkA1[1]);
            const short8 BkA1 = fr4(pkA0[2], pkA1[2], pkA0[3], pkA1[3]);
            const short8 BkB0 = fr4(pkB0[0], pkB1[0], pkB0[1], pkB1[1]);
            const short8 BkB1 = fr4(pkB0[2], pkB1[2], pkB0[3], pkB1[3]);
            // layer 2 MFMA (bias in C operand) + fused epilogue, both groups
            #pragma unroll
            for (int mt = 0; mt < 4; ++mt) {
                const float4  wo4 = *(const float4*)&wo_s[wv * 64 + 16 * mt + 4 * q];
                const float4v c4  = *(const float4v*)&b2_s[wv * 64 + 16 * mt + 4 * q];
                const short8 A20 = fr4(a2f[2 * mt].x, a2f[2 * mt].y,
                                       a2f[2 * mt].z, a2f[2 * mt].w);
                const short8 A21 = fr4(a2f[2 * mt + 1].x, a2f[2 * mt + 1].y,
                                       a2f[2 * mt + 1].z, a2f[2 * mt + 1].w);
                float4v dA = mfma16(A20, BkA0, c4);
                dA = mfma16(A21, BkA1, dA);
                float4v dB = mfma16(A20, BkB0, c4);
                dB = mfma16(A21, BkB1, dB);
                part[0][nt] += wo4.x * fmaxf(dA[0], 0.f)
                             + wo4.y * fmaxf(dA[1], 0.f)
                             + wo4.z * fmaxf(dA[2], 0.f)
                             + wo4.w * fmaxf(dA[3], 0.f);
                part[1][nt] += wo4.x * fmaxf(dB[0], 0.f)
                             + wo4.y * fmaxf(dB[1], 0.f)
                             + wo4.z * fmaxf(dB[2], 0.f)
                             + wo4.w * fmaxf(dB[3], 0.f);
            }
        }
        #pragma unroll
        for (int g = 0; g < 2; ++g)
            #pragma unroll
            for (int nt = 0; nt < 4; ++nt) {
                float s2 = part[g][nt];
                s2 += __shfl_xor(s2, 16, 64);
                s2 += __shfl_xor(s2, 32, 64);
                part[g][nt] = s2;
            }
        float oA = (q == 0) ? part[0][0] : (q == 1) ? part[0][1]
                 : (q == 2) ? part[0][2] : part[0][3];
        float oB = (q == 0) ? part[1][0] : (q == 1) ? part[1][1]
                 : (q == 2) ? part[1][2] : part[1][3];
        oA += bon; oB += bon;

        // exchange: each wave contributes o*mult; dS = w0+w1, dV = w2+w3
        dxch[i & 1][wv][lane]      = oA * multA;
        dxch[i & 1][wv][64 + lane] = oB * multB;
        __syncthreads();
        const float dSA = dxch[i & 1][0][lane]      + dxch[i & 1][1][lane];
        const float dVA = dxch[i & 1][2][lane]      + dxch[i & 1][3][lane];
        const float dSB = dxch[i & 1][0][64 + lane] + dxch[i & 1][1][64 + lane];
        const float dVB = dxch[i & 1][2][64 + lane] + dxch[i & 1][3][64 + lane];
        SA = fmaxf(SA + dSA, 0.0f);
        VA = fmaxf(VA + dVA, 0.0f);
        SB = fmaxf(SB + dSB, 0.0f);
        VB = fmaxf(VB + dVB, 0.0f);

        if (wv == 0) {
            int mm = maskTab[i + 1];
            while (mm) {
                const int qq = __ffs(mm) - 1; mm &= mm - 1;
                float pay = wgtA * fmaxf(SA - ls_k[qq], 0.0f)
                          + wgtB * fmaxf(SB - ls_k[qq], 0.0f);
                #pragma unroll
                for (int off = 32; off > 0; off >>= 1)
                    pay += __shfl_down(pay, off, 64);
                if (lane == 0) atomicAdd(&acc[qq], pay);
            }
        }
    }
}

// ---------- fallback: round-9 dot2 kernel (proven), gated on !flag ----------
__global__ void pack_w(const float* __restrict__ W1, const float* __restrict__ W2,
                       unsigned* __restrict__ wp1, unsigned* __restrict__ wp2) {
    int i = blockIdx.x * 256 + threadIdx.x;
    if (i < 512)              wp1[i] = pkh2(W1[2 * i], W1[2 * i + 1]);
    else if (i < 512 + 8192) { int k = i - 512; wp2[k] = pkh2(W2[2 * k], W2[2 * k + 1]); }
}

__global__ __launch_bounds__(64, 2)
void sde_dot2(const float* __restrict__ x, const float* __restrict__ z,
              const float* __restrict__ z1, const float* __restrict__ b1,
              const float* __restrict__ b2, const float* __restrict__ Wo,
              const float* __restrict__ bo, const uint4* __restrict__ wp1,
              const uint4* __restrict__ wp2, const int* __restrict__ flag,
              float* __restrict__ acc)
{
    if (*flag == 1) return;
    __shared__ __align__(16) uint4 wlds[2176];
    __shared__ float ls_k[NOPTS];
    __shared__ int   maskTab[NSTEPS + 4];
    const int tid = threadIdx.x;
    for (int j = tid; j < 2176; j += 64) wlds[j] = (j < 128) ? wp1[j] : wp2[j - 128];
    for (int jj = tid; jj < NSTEPS + 4; jj += 64) maskTab[jj] = 0;
    if (tid < NOPTS) ls_k[tid] = x[2 * tid + 1];
    __syncthreads();
    if (tid < NOPTS) atomicOr(&maskTab[(int)x[2 * tid]], 1 << tid);
    __syncthreads();
    const int pA = blockIdx.x * 128 + tid, pB = pA + 64;
    const float wgtA = (pA < MPATHS) ? 1.0f : 0.0f;
    const float wgtB = (pB < MPATHS) ? 1.0f : 0.0f;
    int pcA = (pA < MPATHS) ? pA : (MPATHS - 1);
    int pcB = (pB < MPATHS) ? pB : (MPATHS - 1);
    float sgnA = 1.0f, sgnB = 1.0f; int rowA = pcA, rowB = pcB;
    if (pcA >= MC) { sgnA = -1.0f; rowA -= MC; }
    if (pcB >= MC) { sgnB = -1.0f; rowB -= MC; }
    const float* __restrict__ zA  = z  + (size_t)rowA * NSTEPS;
    const float* __restrict__ z1A = z1 + (size_t)rowA * NSTEPS;
    const float* __restrict__ zB  = z  + (size_t)rowB * NSTEPS;
    const float* __restrict__ z1B = z1 + (size_t)rowB * NSTEPS;
    const float hh = 1.0f / 360.0f, sqh = sqrtf(hh);
    const float s75 = 0.86602540378443864676f, rate = 0.025f;
    float SA = 100.0f, VA = 0.04f, SB = 100.0f, VB = 0.04f;
    #pragma unroll 1
    for (int i = 0; i < NSTEPS; ++i) {
        const float zcrA = zA[i], z1rA = z1A[i], zcrB = zB[i], z1rB = z1B[i];
        const float dWA = sqh * (sgnA * zcrA);
        const float dW1A = sqh * (sgnA * (-0.5f * zcrA + s75 * z1rA));
        const float dWB = sqh * (sgnB * zcrB);
        const float dW1B = sqh * (sgnB * (-0.5f * zcrB + s75 * z1rB));
        const float t = (float)i * hh;
        const unsigned inA01 = pkrtz(t, SA), inA23 = pkrtz(VA, rate);
        const unsigned inB01 = pkrtz(t, SB), inB23 = pkrtz(VB, rate);
        float dSA = 0.f, dVA = 0.f, dSB = 0.f, dVB = 0.f;
        #pragma unroll 1
        for (int net = 0; net < 4; ++net) {
            const float* __restrict__ b1n = b1 + net * 64;
            const float* __restrict__ b2n = b2 + net * 64;
            const float* __restrict__ won = Wo + net * 64;
            const uint4* __restrict__ wl1 = &wlds[net * 32];
            const uint4* __restrict__ wl2 = &wlds[128 + net * 512];
            u32x32 hA, hB;
            #pragma unroll
            for (int u = 0; u < 64; u += 2) {
                const uint4 wv = wl1[u >> 1];
                const float bb0 = b1n[u], bb1 = b1n[u + 1];
                float a0 = fdot2(wv.x, inA01, bb0); a0 = fdot2(wv.y, inA23, a0);
                float a1 = fdot2(wv.z, inA01, bb1); a1 = fdot2(wv.w, inA23, a1);
                float c0 = fdot2(wv.x, inB01, bb0); c0 = fdot2(wv.y, inB23, c0);
                float c1 = fdot2(wv.z, inB01, bb1); c1 = fdot2(wv.w, inB23, c1);
                hA[u >> 1] = pkrtz(fmaxf(a0, 0.f), fmaxf(a1, 0.f));
                hB[u >> 1] = pkrtz(fmaxf(c0, 0.f), fmaxf(c1, 0.f));
            }
            float outA = bo[net], outB = outA;
            #pragma unroll 1
            for (int j = 0; j < 64; j += 4) {
                const uint4* __restrict__ r0 = wl2 + (j + 0) * 8;
                const uint4* __restrict__ r1 = wl2 + (j + 1) * 8;
                const uint4* __restrict__ r2 = wl2 + (j + 2) * 8;
                const uint4* __restrict__ r3 = wl2 + (j + 3) * 8;
                float a0 = b2n[j], a1 = b2n[j + 1], a2 = b2n[j + 2], a3 = b2n[j + 3];
                float c0 = a0, c1 = a1, c2 = a2, c3 = a3;
                #pragma unroll
                for (int kk = 0; kk < 8; ++kk) {
                    const uint4 w0 = r0[kk], w1 = r1[kk], w2 = r2[kk], w3 = r3[kk];
                    const unsigned hA0 = hA[4 * kk], hA1 = hA[4 * kk + 1];
                    const unsigned hA2 = hA[4 * kk + 2], hA3 = hA[4 * kk + 3];
                    const unsigned hB0 = hB[4 * kk], hB1 = hB[4 * kk + 1];
                    const unsigned hB2 = hB[4 * kk + 2], hB3 = hB[4 * kk + 3];
                    a0 = fdot2(w0.x, hA0, a0); a0 = fdot2(w0.y, hA1, a0);
                    a0 = fdot2(w0.z, hA2, a0); a0 = fdot2(w0.w, hA3, a0);
                    a1 = fdot2(w1.x, hA0, a1); a1 = fdot2(w1.y, hA1, a1);
                    a1 = fdot2(w1.z, hA2, a1); a1 = fdot2(w1.w, hA3, a1);
                    a2 = fdot2(w2.x, hA0, a2); a2 = fdot2(w2.y, hA1, a2);
                    a2 = fdot2(w2.z, hA2, a2); a2 = fdot2(w2.w, hA3, a2);
                    a3 = fdot2(w3.x, hA0, a3); a3 = fdot2(w3.y, hA1, a3);
                    a3 = fdot2(w3.z, hA2, a3); a3 = fdot2(w3.w, hA3, a3);
                    c0 = fdot2(w0.x, hB0, c0); c0 = fdot2(w0.y, hB1, c0);
                    c0 = fdot2(w0.z, hB2, c0); c0 = fdot2(w0.w, hB3, c0);
                    c1 = fdot2(w1.x, hB0, c1); c1 = fdot2(w1.y, hB1, c1);
                    c1 = fdot2(w1.z, hB2, c1); c1 = fdot2(w1.w, hB3, c1);
                    c2 = fdot2(w2.x, hB0, c2); c2 = fdot2(w2.y, hB1, c2);
                    c2 = fdot2(w2.z, hB2, c2); c2 = fdot2(w2.w, hB3, c2);
                    c3 = fdot2(w3.x, hB0, c3); c3 = fdot2(w3.y, hB1, c3);
                    c3 = fdot2(w3.z, hB2, c3); c3 = fdot2(w3.w, hB3, c3);
                }
                const float wo0 = won[j], wo1 = won[j + 1];
                const float wo2 = won[j + 2], wo3 = won[j + 3];
                outA = fmaf(wo0, fmaxf(a0, 0.f), outA); outA = fmaf(wo1, fmaxf(a1, 0.f), outA);
                outA = fmaf(wo2, fmaxf(a2, 0.f), outA); outA = fmaf(wo3, fmaxf(a3, 0.f), outA);
                outB = fmaf(wo0, fmaxf(c0, 0.f), outB); outB = fmaf(wo1, fmaxf(c1, 0.f), outB);
                outB = fmaf(wo2, fmaxf(c2, 0.f), outB); outB = fmaf(wo3, fmaxf(c3, 0.f), outB);
            }
            const float msA = (net == 0) ? hh : (net == 1) ? dWA  : 0.0f;
            const float mvA = (net == 2) ? hh : (net == 3) ? dW1A : 0.0f;
            const float msB = (net == 0) ? hh : (net == 1) ? dWB  : 0.0f;
            const float mvB = (net == 2) ? hh : (net == 3) ? dW1B : 0.0f;
            dSA = fmaf(outA, msA, dSA); dVA = fmaf(outA, mvA, dVA);
            dSB = fmaf(outB, msB, dSB); dVB = fmaf(outB, mvB, dVB);
        }
        SA = fmaxf(SA + dSA, 0.f); VA = fmaxf(VA + dVA, 0.f);
        SB = fmaxf(SB + dSB, 0.f); VB = fmaxf(VB + dVB, 0.f);
        int mm = maskTab[i + 1];
        while (mm) {
            const int qq = __ffs(mm) - 1; mm &= mm - 1;
            float pay = wgtA * fmaxf(SA - ls_k[qq], 0.f) + wgtB * fmaxf(SB - ls_k[qq], 0.f);
            #pragma unroll
            for (int off = 32; off > 0; off >>= 1)
                pay += __shfl_down(pay, off, 64);
            if (tid == 0) atomicAdd(&acc[qq], pay);
        }
    }
}

__global__ void price_kernel(const float* __restrict__ x, const float* __restrict__ acc,
                             float* __restrict__ out) {
    const int q = threadIdx.x;
    if (q < NOPTS) {
        const float mat = x[q * 2];
        out[q] = acc[q] * (1.0f / (float)MPATHS) * expf((-0.025f * mat) / 360.0f);
    }
}

extern "C" void kernel_launch(void* const* d_in, const int* in_sizes, int n_in,
                              void* d_out, int out_size, void* d_ws, size_t ws_size,
                              hipStream_t stream)
{
    const float* x  = (const float*)d_in[0];
    const float* z  = (const float*)d_in[1];
    const float* z1 = (const float*)d_in[2];
    const float* W1 = (const float*)d_in[3];
    const float* b1 = (const float*)d_in[4];
    const float* W2 = (const float*)d_in[5];
    const float* b2 = (const float*)d_in[6];
    const float* Wo = (const float*)d_in[7];
    const float* bo = (const float*)d_in[8];

    char* ws = (char*)d_ws;
    float*    acc  = (float*)ws;                 // 128 B
    int*      flag = (int*)(ws + 256);
    int*      tbl  = (int*)(ws + 1024);          // 8.3 KB tables (incl. Minv)
    uint4*    w1f  = (uint4*)(ws + 16384);       // 16 KB
    uint4*    w2f  = (uint4*)(ws + 32768);       // 32 KB
    unsigned* wp1  = (unsigned*)(ws + 65536);    // 2 KB
    unsigned* wp2  = wp1 + 512;                  // 32 KB

    (void)hipMemsetAsync(acc, 0, NOPTS * sizeof(float), stream);
    pack_w<<<(512 + 8192 + 255) / 256, 256, 0, stream>>>(W1, W2, wp1, wp2);
    probe_mn<<<1, 64, 0, stream>>>(tbl);
    probe_k<<<512, 64, 0, stream>>>(tbl);
    finalize_verify<<<1, 64, 0, stream>>>(tbl, flag);
    build_frags<<<12, 256, 0, stream>>>(W1, b1, W2, tbl, w1f, w2f);

    const int gridS = (MPATHS + 127) / 128;  // 782 blocks x 4 waves, 2 groups/block
    sde_mfma_w4<<<gridS, 256, 0, stream>>>(x, z, z1, b2, Wo, bo, tbl, w1f, w2f, flag, acc);
    const int gridF = (MPATHS + 127) / 128;  // 782 (fallback)
    sde_dot2<<<gridF, 64, 0, stream>>>(x, z, z1, b1, b2, Wo, bo,
                                       (const uint4*)wp1, (const uint4*)wp2, flag, acc);
    price_kernel<<<1, 64, 0, stream>>>(x, acc, (float*)d_out);
}

// Round 6
// 1569.566 us; speedup vs baseline: 1.0972x; 1.0972x over previous
//
#include <hip/hip_runtime.h>
#include <math.h>

#define MC      50000
#define MPATHS  100000
#define NSTEPS  180
#define NOPTS   32

typedef __attribute__((ext_vector_type(8))) short short8;
typedef __attribute__((ext_vector_type(4))) float float4v;
typedef _Float16 half2v __attribute__((ext_vector_type(2)));
typedef unsigned u32x32 __attribute__((ext_vector_type(32)));

// ---------- helpers ----------
static __device__ __forceinline__ unsigned bf16u(float x) {        // RNE
    unsigned u = __float_as_uint(x);
    return (u + 0x7fffu + ((u >> 16) & 1u)) >> 16;
}
static __device__ __forceinline__ float bf16val(float x) {
    return __uint_as_float(bf16u(x) << 16);
}
static __device__ __forceinline__ unsigned pkh2(float a, float b) { // f16 pair (fallback path)
    half2v h; h.x = (_Float16)a; h.y = (_Float16)b;
    return __builtin_bit_cast(unsigned, h);
}
static __device__ __forceinline__ unsigned pkrtz(float a, float b) {
    auto h = __builtin_amdgcn_cvt_pkrtz(a, b);
    return __builtin_bit_cast(unsigned, h);
}
static __device__ __forceinline__ float fdot2(unsigned w, unsigned h, float c) {
    return __builtin_amdgcn_fdot2(__builtin_bit_cast(half2v, w),
                                  __builtin_bit_cast(half2v, h), c, false);
}
static __device__ __forceinline__ short8 fr4(unsigned a, unsigned b,
                                             unsigned c, unsigned d) {
    union { unsigned u[4]; short8 s; } t;
    t.u[0] = a; t.u[1] = b; t.u[2] = c; t.u[3] = d;
    return t.s;
}
static __device__ __forceinline__ float4v mfma16(short8 a, short8 b, float4v c) {
    return __builtin_amdgcn_mfma_f32_16x16x32_bf16(a, b, c, 0, 0, 0);
}

// ws table region (ints): [0..511]=mA  [512..1023]=kA(kid->rank)
//                          [1024..1535]=nB  [1536..2047]=kB(kid->rank)
//                          [2048..2079]=Minv (k-rank -> W2 local column, fast path)

// ---------- probe 1: m-map (A) and n-map (B); trusts only C/D layout ----------
__global__ void probe_mn(int* tbl) {
    const int lane = threadIdx.x;
    for (int s = lane; s < 2048; s += 64) tbl[s] = 0;   // defaults (safe clamp later)
    const float4v z4 = {0.f, 0.f, 0.f, 0.f};
    for (int L = 0; L < 64; ++L)
        for (int j = 0; j < 8; ++j) {
            unsigned au[4] = {0u, 0u, 0u, 0u};
            if (lane == L) au[j >> 1] = 0x3F80u << (16 * (j & 1));
            short8 a = fr4(au[0], au[1], au[2], au[3]);
            short8 b = fr4(0x3F803F80u, 0x3F803F80u, 0x3F803F80u, 0x3F803F80u);
            float4v d = mfma16(a, b, z4);
            if ((lane & 15) == 0) {
                #pragma unroll
                for (int r = 0; r < 4; ++r)
                    if (d[r] != 0.0f) tbl[L * 8 + j] = (lane >> 4) * 4 + r;
            }
        }
    for (int L = 0; L < 64; ++L)
        for (int j = 0; j < 8; ++j) {
            unsigned bu[4] = {0u, 0u, 0u, 0u};
            if (lane == L) bu[j >> 1] = 0x3F80u << (16 * (j & 1));
            short8 a = fr4(0x3F803F80u, 0x3F803F80u, 0x3F803F80u, 0x3F803F80u);
            short8 b = fr4(bu[0], bu[1], bu[2], bu[3]);
            float4v d = mfma16(a, b, z4);
            if ((lane >> 4) == 0 && d[0] != 0.0f) tbl[1024 + L * 8 + j] = (lane & 15);
        }
}

// ---------- probe 2: k-equivalence classes between A-slots and B-slots ----------
__global__ void probe_k(int* tbl) {
    const int lane = threadIdx.x;
    const int sA = blockIdx.x;              // 0..511
    const float4v z4 = {0.f, 0.f, 0.f, 0.f};
    unsigned au[4] = {0u, 0u, 0u, 0u};
    if (lane == (sA >> 3)) au[(sA & 7) >> 1] = 0x3F80u << (16 * (sA & 1));
    short8 a = fr4(au[0], au[1], au[2], au[3]);
    int kid = -1;
    for (int sB = 0; sB < 512; ++sB) {
        unsigned bu[4] = {0u, 0u, 0u, 0u};
        const int LB = sB >> 3, jB = sB & 7;
        if (lane == LB) bu[jB >> 1] = 0x3F80u << (16 * (jB & 1));
        short8 b = fr4(bu[0], bu[1], bu[2], bu[3]);
        float4v d = mfma16(a, b, z4);
        bool hit = (d[0] != 0.f) | (d[1] != 0.f) | (d[2] != 0.f) | (d[3] != 0.f);
        if (__any(hit)) {
            if (kid < 0) kid = sB;
            if (lane == 0) tbl[1536 + sB] = kid;   // benign same-value races
        }
    }
    if (lane == 0) tbl[512 + sA] = (kid < 0) ? 0 : kid;
}

// ---------- probe 3: rank k-classes; verify layout stack + fast-path conditions ----------
// Fast path additionally requires (checked exactly):
//   (a) B n-map standard: nb(lane,j) == lane&15
//   (b) B k-ranks independent of lane&15 (function of (g=lane>>4, j) only)
//   (c) (g,j) -> rank bijective onto 0..31
// Then Minv[rank(g,j)] = 16*((j>>2)&1) + 4*g + 2*((j>>1)&1) + (j&1) re-indexes W2
// columns so layer-2's B fragment equals layer-1's packed D registers verbatim.
__global__ void finalize_verify(int* tbl, int* flag) {
    __shared__ int cnt[32];
    __shared__ int minv[32];
    const int lane = threadIdx.x;
    if (lane < 32) { cnt[lane] = 0; minv[lane] = 0; }
    int rA[8], rB[8];
    #pragma unroll
    for (int j = 0; j < 8; ++j) {
        const int s = lane * 8 + j;
        const int kidA = tbl[512 + s], kidB = tbl[1536 + s];
        int ra = 0, rb = 0;
        for (int u = 0; u < 512; ++u) {
            const int canon = (tbl[1536 + u] == u);
            ra += canon & (u < kidA);
            rb += canon & (u < kidB);
        }
        rA[j] = ra & 31; rB[j] = rb & 31;
    }
    __syncthreads();
    #pragma unroll
    for (int j = 0; j < 8; ++j) {
        tbl[512 + lane * 8 + j]  = rA[j];
        tbl[1536 + lane * 8 + j] = rB[j];
    }
    // verify: integer GEMM through discovered tables, exact compare
    unsigned au[4] = {0u, 0u, 0u, 0u}, bu[4] = {0u, 0u, 0u, 0u};
    #pragma unroll
    for (int j = 0; j < 8; ++j) {
        const int s = lane * 8 + j;
        const int m = tbl[s] & 15, ka = rA[j];
        const int n = tbl[1024 + s] & 15, kb = rB[j];
        const int fv = ((m * 7 + ka * 3) % 5) - 2;
        const int gv = ((kb * 5 + n * 11) % 7) - 3;
        au[j >> 1] |= bf16u((float)fv) << (16 * (j & 1));
        bu[j >> 1] |= bf16u((float)gv) << (16 * (j & 1));
    }
    const float4v z4 = {0.f, 0.f, 0.f, 0.f};
    float4v d = mfma16(fr4(au[0], au[1], au[2], au[3]),
                       fr4(bu[0], bu[1], bu[2], bu[3]), z4);
    const int col = lane & 15;
    bool ok = true;
    #pragma unroll
    for (int r = 0; r < 4; ++r) {
        const int row = (lane >> 4) * 4 + r;
        int ref = 0;
        for (int k = 0; k < 32; ++k)
            ref += (((row * 7 + k * 3) % 5) - 2) * (((k * 5 + col * 11) % 7) - 3);
        ok = ok && (d[r] == (float)ref);
    }
    // fast-path conditions (a),(b)
    bool okf = ok;
    #pragma unroll
    for (int j = 0; j < 8; ++j) {
        okf = okf && ((tbl[1024 + lane * 8 + j] & 15) == (lane & 15));
        const int ref = __shfl(rB[j], lane & 48, 64);
        okf = okf && (rB[j] == ref);
    }
    // (c) bijectivity + Minv build (c==0 lanes cover all 32 (g,j) positions)
    if ((lane & 15) == 0) {
        const int g = lane >> 4;
        #pragma unroll
        for (int j = 0; j < 8; ++j) {
            atomicAdd(&cnt[rB[j]], 1);
            minv[rB[j]] = 16 * ((j >> 2) & 1) + 4 * g + 2 * ((j >> 1) & 1) + (j & 1);
        }
    }
    __syncthreads();
    if (lane < 32) {
        okf = okf && (cnt[lane] == 1);
        tbl[2048 + lane] = minv[lane];
    }
    const bool allok = __all(okf);
    if (lane == 0) *flag = allok ? 1 : 0;
}

// ---------- build W1/W2 A-fragment tables (after verify tables final) ----------
// W2 columns permuted by Minv so layer-2 B-frag == layer-1 packed D registers.
__global__ void build_frags(const float* __restrict__ W1, const float* __restrict__ b1,
                            const float* __restrict__ W2, const int* __restrict__ tbl,
                            uint4* __restrict__ w1f, uint4* __restrict__ w2f) {
    const int t = blockIdx.x * 256 + threadIdx.x;   // 0..3071
    if (t >= 3072) return;
    const int lane = t & 63, frag = t >> 6;
    const float rateB = bf16val(0.025f);
    unsigned u[4] = {0u, 0u, 0u, 0u};
    if (frag < 16) {            // W1: net=frag>>2, mt=frag&3 ; k 0..5 hi, 6..11 lo-residual
        const int net = frag >> 2, mt = frag & 3;
        #pragma unroll
        for (int j = 0; j < 8; ++j) {
            const int s = lane * 8 + j;
            const int m = tbl[s] & 15, k = tbl[512 + s] & 31;
            unsigned bits = 0u;
            if (k < 12) {
                const int kk = (k < 6) ? k : k - 6;
                const int M = net * 64 + 16 * mt + m;
                float v;
                if (kk == 0)                 v = W1[M * 4 + 0];
                else if (kk == 1 || kk == 4) v = W1[M * 4 + 1];
                else if (kk == 2 || kk == 5) v = W1[M * 4 + 2];
                else                         v = W1[M * 4 + 3] + b1[M] / rateB;
                bits = (k < 6) ? bf16u(v) : bf16u(v - bf16val(v));
            }
            u[j >> 1] |= bits << (16 * (j & 1));
        }
        w1f[frag * 64 + lane] = make_uint4(u[0], u[1], u[2], u[3]);
    } else {                    // W2: f2=frag-16: net=f2>>3, mt=(f2>>1)&3, kc=f2&1
        const int f2 = frag - 16;
        const int net = f2 >> 3, mt = (f2 >> 1) & 3, kc = f2 & 1;
        #pragma unroll
        for (int j = 0; j < 8; ++j) {
            const int s = lane * 8 + j;
            const int m = tbl[s] & 15, k = tbl[512 + s] & 31;
            const float v = W2[(net * 64 + 16 * mt + m) * 64 + 32 * kc + tbl[2048 + k]];
            u[j >> 1] |= bf16u(v) << (16 * (j & 1));
        }
        w2f[f2 * 64 + lane] = make_uint4(u[0], u[1], u[2], u[3]);
    }
}

// ---------- main MFMA path-sim: 4 waves/block, 1 net per wave, LDS-free B1 ----------
// Round-4 structure (best verified: 1522 us) + two latency fixes:
//  (1) z/z1 loaded as per-lane float4 chunks (4 steps) with one-chunk-ahead
//      prefetch: the per-step 64-line uncoalesced gather (720 B path stride,
//      L1-thrashing, L2-latency on the critical path) becomes one hidden
//      prefetch per 4 steps. Waves 0/2 load nothing; wave 1 z only.
//  (2) wo4/b2 C-operand LDS reads hoisted to registers (per-thread constant).
__global__ __launch_bounds__(256, 3)
void sde_mfma_w4(const float* __restrict__ x, const float* __restrict__ z,
                 const float* __restrict__ z1, const float* __restrict__ b2,
                 const float* __restrict__ Wo, const float* __restrict__ bo,
                 const int* __restrict__ tbl, const uint4* __restrict__ w1f,
                 const uint4* __restrict__ w2f, const int* __restrict__ flag,
                 float* __restrict__ acc)
{
    if (*flag != 1) return;
    __shared__ __align__(16) float wo_s[256];
    __shared__ __align__(16) float b2_s[256];
    __shared__ float dxch[2][4][64];
    __shared__ float ls_k[NOPTS];
    __shared__ int   maskTab[NSTEPS + 4];

    const int tid = threadIdx.x;
    const int wv = tid >> 6, lane = tid & 63;   // wv == net index
    const int q = lane >> 4, c = lane & 15;

    for (int j = tid; j < 256; j += 256) { wo_s[j] = Wo[j]; b2_s[j] = b2[j]; }
    for (int j = tid; j < NSTEPS + 4; j += 256) maskTab[j] = 0;
    if (tid < NOPTS) ls_k[tid] = x[2 * tid + 1];
    __syncthreads();
    if (tid < NOPTS) atomicOr(&maskTab[(int)x[2 * tid]], 1 << tid);
    __syncthreads();

    // per-lane B1 assembly tables from discovered k-map
    // rows: 0=t 1=S 2=V 3=rate 4=Sres 5=Vres 6=zero
    const unsigned rate16 = bf16u(0.025f);
    unsigned selAB[4], dynM[4], cU[4], mT[4];
    {
        int rowj[8];
        #pragma unroll
        for (int j = 0; j < 8; ++j) {
            const int kb = tbl[1536 + lane * 8 + j] & 31;
            rowj[j] = (kb < 6) ? kb : ((kb < 12) ? kb - 6 : 6);
        }
        #pragma unroll
        for (int w = 0; w < 4; ++w) {
            unsigned s = 0, d = 0, cu = 0, mt_ = 0;
            #pragma unroll
            for (int h = 0; h < 2; ++h) {
                const int r = rowj[2 * w + h];
                unsigned hs = 0x0504u, hd = 0u, hcu = 0u, hmt = 0u;
                if      (r == 1) { hs = 0x0504u; hd = 0xFFFFu; }   // S  = Ap lo16
                else if (r == 2) { hs = 0x0706u; hd = 0xFFFFu; }   // V  = Ap hi16
                else if (r == 4) { hs = 0x0100u; hd = 0xFFFFu; }   // Sr = Bp lo16
                else if (r == 5) { hs = 0x0302u; hd = 0xFFFFu; }   // Vr = Bp hi16
                else if (r == 0) { hmt = 0xFFFFu; }                // t (per-step)
                else if (r == 3) { hcu = rate16; }                 // rate const
                // r==6: zero
                s  |= hs  << (16 * h); d   |= hd  << (16 * h);
                cu |= hcu << (16 * h); mt_ |= hmt << (16 * h);
            }
            selAB[w] = s; dynM[w] = d; cU[w] = cu; mT[w] = mt_;
        }
    }

    const int p_ = blockIdx.x * 64 + lane;      // 64 paths per block
    const float wgt = (p_ < MPATHS) ? 1.0f : 0.0f;
    int pc = (p_ < MPATHS) ? p_ : (MPATHS - 1);
    float sgn = 1.0f; int row_ = pc;
    if (pc >= MC) { sgn = -1.0f; row_ -= MC; }
    const float* __restrict__ zrow  = z  + (size_t)row_ * NSTEPS;
    const float* __restrict__ z1row = z1 + (size_t)row_ * NSTEPS;

    const float hh = 1.0f / 360.0f, sqh = sqrtf(hh);
    const float s75 = 0.86602540378443864676f;
    const float bon = bo[wv];

    // hoisted A fragments for this wave's net (held in VGPRs across all steps)
    uint4 a1f[4], a2f[8];
    #pragma unroll
    for (int mt = 0; mt < 4; ++mt) {
        a1f[mt]         = w1f[(wv * 4 + mt) * 64 + lane];
        a2f[2 * mt]     = w2f[((wv * 4 + mt) * 2 + 0) * 64 + lane];
        a2f[2 * mt + 1] = w2f[((wv * 4 + mt) * 2 + 1) * 64 + lane];
    }
    // hoisted per-thread-constant epilogue operands (were per-step LDS reads)
    float4  wo4r[4];
    float4v c4r[4];
    #pragma unroll
    for (int mt = 0; mt < 4; ++mt) {
        wo4r[mt] = *(const float4*)&wo_s[wv * 64 + 16 * mt + 4 * q];
        c4r[mt]  = *(const float4v*)&b2_s[wv * 64 + 16 * mt + 4 * q];
    }

    float S = 100.0f, V = 0.04f;

    // z/z1 chunk state: 4 steps per chunk, prefetch one chunk ahead
    const bool needZ  = (wv == 1) | (wv == 3);
    const bool needZ1 = (wv == 3);
    float4 zc = {0.f, 0.f, 0.f, 0.f}, z1c = {0.f, 0.f, 0.f, 0.f};
    float4 zn = zc, z1n = z1c;
    if (needZ)  zc  = *(const float4*)(zrow);
    if (needZ1) z1c = *(const float4*)(z1row);

    #pragma unroll 1
    for (int ch = 0; ch < NSTEPS / 4; ++ch) {
        // prefetch next chunk (latency hidden under this chunk's 4 steps)
        if (ch + 1 < NSTEPS / 4) {
            if (needZ)  zn  = *(const float4*)(zrow  + 4 * (ch + 1));
            if (needZ1) z1n = *(const float4*)(z1row + 4 * (ch + 1));
        }
        #pragma unroll
        for (int ii = 0; ii < 4; ++ii) {
            const int i = 4 * ch + ii;
            const float zz  = (ii == 0) ? zc.x  : (ii == 1) ? zc.y  : (ii == 2) ? zc.z  : zc.w;
            const float zz1 = (ii == 0) ? z1c.x : (ii == 1) ? z1c.y : (ii == 2) ? z1c.z : z1c.w;
            // per-wave multiplier of this net's output
            float mult;
            if      (wv == 1) mult = sqh * (sgn * zz);
            else if (wv == 3) mult = sqh * (sgn * (-0.5f * zz + s75 * zz1));
            else              mult = hh;

            const float t = (float)i * hh;
            const unsigned tB = bf16u(t);
            const unsigned tB2 = tB | (tB << 16);
            unsigned UW[4];
            #pragma unroll
            for (int w = 0; w < 4; ++w) UW[w] = cU[w] | (mT[w] & tB2);

            // per-lane packed state words (own path)
            const unsigned Shu = bf16u(S), Vhu = bf16u(V);
            const unsigned PA = Shu | (Vhu << 16);
            const float Sr = S - __uint_as_float(Shu << 16);
            const float Vr = V - __uint_as_float(Vhu << 16);
            const unsigned PB = __builtin_amdgcn_perm(__float_as_uint(Vr),
                                                      __float_as_uint(Sr), 0x07060302u);

            // B1 fragments fully in-register: 2 bpermute + 12 VALU per nt-tile
            unsigned B1[4][4];
            #pragma unroll
            for (int nt = 0; nt < 4; ++nt) {
                const int a = (nt << 6) | (c << 2);
                const unsigned Ap = (unsigned)__builtin_amdgcn_ds_bpermute(a, (int)PA);
                const unsigned Bp = (unsigned)__builtin_amdgcn_ds_bpermute(a, (int)PB);
                #pragma unroll
                for (int w = 0; w < 4; ++w)
                    B1[nt][w] = (__builtin_amdgcn_perm(Ap, Bp, selAB[w]) & dynM[w]) | UW[w];
            }

            float part[4] = {0.f, 0.f, 0.f, 0.f};
            const float4v z4 = {0.f, 0.f, 0.f, 0.f};
            #pragma unroll
            for (int nt = 0; nt < 4; ++nt) {
                // ---- layer 1 MFMA -> relu -> bf16 perm-pack (registers only) ----
                unsigned pk0[4], pk1[4];
                #pragma unroll
                for (int mt = 0; mt < 4; ++mt) {
                    float4v d = mfma16(fr4(a1f[mt].x, a1f[mt].y, a1f[mt].z, a1f[mt].w),
                                       fr4(B1[nt][0], B1[nt][1], B1[nt][2], B1[nt][3]), z4);
                    const unsigned r0 = __float_as_uint(fmaxf(d[0], 0.f));
                    const unsigned r1 = __float_as_uint(fmaxf(d[1], 0.f));
                    const unsigned r2 = __float_as_uint(fmaxf(d[2], 0.f));
                    const unsigned r3 = __float_as_uint(fmaxf(d[3], 0.f));
                    pk0[mt] = __builtin_amdgcn_perm(r1, r0, 0x07060302u);
                    pk1[mt] = __builtin_amdgcn_perm(r3, r2, 0x07060302u);
                }
                // layer-2 B fragments are the packed registers verbatim
                const short8 Bk0 = fr4(pk0[0], pk1[0], pk0[1], pk1[1]);
                const short8 Bk1 = fr4(pk0[2], pk1[2], pk0[3], pk1[3]);
                // ---- layer 2 MFMA (bias in C operand) + fused epilogue ----
                #pragma unroll
                for (int mt = 0; mt < 4; ++mt) {
                    float4v d = mfma16(fr4(a2f[2 * mt].x, a2f[2 * mt].y,
                                           a2f[2 * mt].z, a2f[2 * mt].w), Bk0, c4r[mt]);
                    d = mfma16(fr4(a2f[2 * mt + 1].x, a2f[2 * mt + 1].y,
                                   a2f[2 * mt + 1].z, a2f[2 * mt + 1].w), Bk1, d);
                    part[nt] += wo4r[mt].x * fmaxf(d[0], 0.f)
                              + wo4r[mt].y * fmaxf(d[1], 0.f)
                              + wo4r[mt].z * fmaxf(d[2], 0.f)
                              + wo4r[mt].w * fmaxf(d[3], 0.f);
                }
            }
            #pragma unroll
            for (int nt = 0; nt < 4; ++nt) {
                float s2 = part[nt];
                s2 += __shfl_xor(s2, 16, 64);
                s2 += __shfl_xor(s2, 32, 64);
                part[nt] = s2;
            }
            float o = (q == 0) ? part[0] : (q == 1) ? part[1] : (q == 2) ? part[2] : part[3];
            o += bon;

            // exchange: each wave contributes o*mult; dS = w0+w1, dV = w2+w3
            dxch[i & 1][wv][lane] = o * mult;
            __syncthreads();
            const float dS = dxch[i & 1][0][lane] + dxch[i & 1][1][lane];
            const float dV = dxch[i & 1][2][lane] + dxch[i & 1][3][lane];
            S = fmaxf(S + dS, 0.0f);
            V = fmaxf(V + dV, 0.0f);

            if (wv == 0) {
                int mm = maskTab[i + 1];
                while (mm) {
                    const int qq = __ffs(mm) - 1; mm &= mm - 1;
                    float pay = wgt * fmaxf(S - ls_k[qq], 0.0f);
                    #pragma unroll
                    for (int off = 32; off > 0; off >>= 1)
                        pay += __shfl_down(pay, off, 64);
                    if (lane == 0) atomicAdd(&acc[qq], pay);
                }
            }
        }
        zc = zn; z1c = z1n;
    }
}

// ---------- fallback: round-9 dot2 kernel (proven), gated on !flag ----------
__global__ void pack_w(const float* __restrict__ W1, const float* __restrict__ W2,
                       unsigned* __restrict__ wp1, unsigned* __restrict__ wp2) {
    int i = blockIdx.x * 256 + threadIdx.x;
    if (i < 512)              wp1[i] = pkh2(W1[2 * i], W1[2 * i + 1]);
    else if (i < 512 + 8192) { int k = i - 512; wp2[k] = pkh2(W2[2 * k], W2[2 * k + 1]); }
}

__global__ __launch_bounds__(64, 2)
void sde_dot2(const float* __restrict__ x, const float* __restrict__ z,
              const float* __restrict__ z1, const float* __restrict__ b1,
              const float* __restrict__ b2, const float* __restrict__ Wo,
              const float* __restrict__ bo, const uint4* __restrict__ wp1,
              const uint4* __restrict__ wp2, const int* __restrict__ flag,
              float* __restrict__ acc)
{
    if (*flag == 1) return;
    __shared__ __align__(16) uint4 wlds[2176];
    __shared__ float ls_k[NOPTS];
    __shared__ int   maskTab[NSTEPS + 4];
    const int tid = threadIdx.x;
    for (int j = tid; j < 2176; j += 64) wlds[j] = (j < 128) ? wp1[j] : wp2[j - 128];
    for (int jj = tid; jj < NSTEPS + 4; jj += 64) maskTab[jj] = 0;
    if (tid < NOPTS) ls_k[tid] = x[2 * tid + 1];
    __syncthreads();
    if (tid < NOPTS) atomicOr(&maskTab[(int)x[2 * tid]], 1 << tid);
    __syncthreads();
    const int pA = blockIdx.x * 128 + tid, pB = pA + 64;
    const float wgtA = (pA < MPATHS) ? 1.0f : 0.0f;
    const float wgtB = (pB < MPATHS) ? 1.0f : 0.0f;
    int pcA = (pA < MPATHS) ? pA : (MPATHS - 1);
    int pcB = (pB < MPATHS) ? pB : (MPATHS - 1);
    float sgnA = 1.0f, sgnB = 1.0f; int rowA = pcA, rowB = pcB;
    if (pcA >= MC) { sgnA = -1.0f; rowA -= MC; }
    if (pcB >= MC) { sgnB = -1.0f; rowB -= MC; }
    const float* __restrict__ zA  = z  + (size_t)rowA * NSTEPS;
    const float* __restrict__ z1A = z1 + (size_t)rowA * NSTEPS;
    const float* __restrict__ zB  = z  + (size_t)rowB * NSTEPS;
    const float* __restrict__ z1B = z1 + (size_t)rowB * NSTEPS;
    const float hh = 1.0f / 360.0f, sqh = sqrtf(hh);
    const float s75 = 0.86602540378443864676f, rate = 0.025f;
    float SA = 100.0f, VA = 0.04f, SB = 100.0f, VB = 0.04f;
    #pragma unroll 1
    for (int i = 0; i < NSTEPS; ++i) {
        const float zcrA = zA[i], z1rA = z1A[i], zcrB = zB[i], z1rB = z1B[i];
        const float dWA = sqh * (sgnA * zcrA);
        const float dW1A = sqh * (sgnA * (-0.5f * zcrA + s75 * z1rA));
        const float dWB = sqh * (sgnB * zcrB);
        const float dW1B = sqh * (sgnB * (-0.5f * zcrB + s75 * z1rB));
        const float t = (float)i * hh;
        const unsigned inA01 = pkrtz(t, SA), inA23 = pkrtz(VA, rate);
        const unsigned inB01 = pkrtz(t, SB), inB23 = pkrtz(VB, rate);
        float dSA = 0.f, dVA = 0.f, dSB = 0.f, dVB = 0.f;
        #pragma unroll 1
        for (int net = 0; net < 4; ++net) {
            const float* __restrict__ b1n = b1 + net * 64;
            const float* __restrict__ b2n = b2 + net * 64;
            const float* __restrict__ won = Wo + net * 64;
            const uint4* __restrict__ wl1 = &wlds[net * 32];
            const uint4* __restrict__ wl2 = &wlds[128 + net * 512];
            u32x32 hA, hB;
            #pragma unroll
            for (int u = 0; u < 64; u += 2) {
                const uint4 wv = wl1[u >> 1];
                const float bb0 = b1n[u], bb1 = b1n[u + 1];
                float a0 = fdot2(wv.x, inA01, bb0); a0 = fdot2(wv.y, inA23, a0);
                float a1 = fdot2(wv.z, inA01, bb1); a1 = fdot2(wv.w, inA23, a1);
                float c0 = fdot2(wv.x, inB01, bb0); c0 = fdot2(wv.y, inB23, c0);
                float c1 = fdot2(wv.z, inB01, bb1); c1 = fdot2(wv.w, inB23, c1);
                hA[u >> 1] = pkrtz(fmaxf(a0, 0.f), fmaxf(a1, 0.f));
                hB[u >> 1] = pkrtz(fmaxf(c0, 0.f), fmaxf(c1, 0.f));
            }
            float outA = bo[net], outB = outA;
            #pragma unroll 1
            for (int j = 0; j < 64; j += 4) {
                const uint4* __restrict__ r0 = wl2 + (j + 0) * 8;
                const uint4* __restrict__ r1 = wl2 + (j + 1) * 8;
                const uint4* __restrict__ r2 = wl2 + (j + 2) * 8;
                const uint4* __restrict__ r3 = wl2 + (j + 3) * 8;
                float a0 = b2n[j], a1 = b2n[j + 1], a2 = b2n[j + 2], a3 = b2n[j + 3];
                float c0 = a0, c1 = a1, c2 = a2, c3 = a3;
                #pragma unroll
                for (int kk = 0; kk < 8; ++kk) {
                    const uint4 w0 = r0[kk], w1 = r1[kk], w2 = r2[kk], w3 = r3[kk];
                    const unsigned hA0 = hA[4 * kk], hA1 = hA[4 * kk + 1];
                    const unsigned hA2 = hA[4 * kk + 2], hA3 = hA[4 * kk + 3];
                    const unsigned hB0 = hB[4 * kk], hB1 = hB[4 * kk + 1];
                    const unsigned hB2 = hB[4 * kk + 2], hB3 = hB[4 * kk + 3];
                    a0 = fdot2(w0.x, hA0, a0); a0 = fdot2(w0.y, hA1, a0);
                    a0 = fdot2(w0.z, hA2, a0); a0 = fdot2(w0.w, hA3, a0);
                    a1 = fdot2(w1.x, hA0, a1); a1 = fdot2(w1.y, hA1, a1);
                    a1 = fdot2(w1.z, hA2, a1); a1 = fdot2(w1.w, hA3, a1);
                    a2 = fdot2(w2.x, hA0, a2); a2 = fdot2(w2.y, hA1, a2);
                    a2 = fdot2(w2.z, hA2, a2); a2 = fdot2(w2.w, hA3, a2);
                    a3 = fdot2(w3.x, hA0, a3); a3 = fdot2(w3.y, hA1, a3);
                    a3 = fdot2(w3.z, hA2, a3); a3 = fdot2(w3.w, hA3, a3);
                    c0 = fdot2(w0.x, hB0, c0); c0 = fdot2(w0.y, hB1, c0);
                    c0 = fdot2(w0.z, hB2, c0); c0 = fdot2(w0.w, hB3, c0);
                    c1 = fdot2(w1.x, hB0, c1); c1 = fdot2(w1.y, hB1, c1);
                    c1 = fdot2(w1.z, hB2, c1); c1 = fdot2(w1.w, hB3, c1);
                    c2 = fdot2(w2.x, hB0, c2); c2 = fdot2(w2.y, hB1, c2);
                    c2 = fdot2(w2.z, hB2, c2); c2 = fdot2(w2.w, hB3, c2);
                    c3 = fdot2(w3.x, hB0, c3); c3 = fdot2(w3.y, hB1, c3);
                    c3 = fdot2(w3.z, hB2, c3); c3 = fdot2(w3.w, hB3, c3);
                }
                const float wo0 = won[j], wo1 = won[j + 1];
                const float wo2 = won[j + 2], wo3 = won[j + 3];
                outA = fmaf(wo0, fmaxf(a0, 0.f), outA); outA = fmaf(wo1, fmaxf(a1, 0.f), outA);
                outA = fmaf(wo2, fmaxf(a2, 0.f), outA); outA = fmaf(wo3, fmaxf(a3, 0.f), outA);
                outB = fmaf(wo0, fmaxf(c0, 0.f), outB); outB = fmaf(wo1, fmaxf(c1, 0.f), outB);
                outB = fmaf(wo2, fmaxf(c2, 0.f), outB); outB = fmaf(wo3, fmaxf(c3, 0.f), outB);
            }
            const float msA = (net == 0) ? hh : (net == 1) ? dWA  : 0.0f;
            const float mvA = (net == 2) ? hh : (net == 3) ? dW1A : 0.0f;
            const float msB = (net == 0) ? hh : (net == 1) ? dWB  : 0.0f;
            const float mvB = (net == 2) ? hh : (net == 3) ? dW1B : 0.0f;
            dSA = fmaf(outA, msA, dSA); dVA = fmaf(outA, mvA, dVA);
            dSB = fmaf(outB, msB, dSB); dVB = fmaf(outB, mvB, dVB);
        }
        SA = fmaxf(SA + dSA, 0.f); VA = fmaxf(VA + dVA, 0.f);
        SB = fmaxf(SB + dSB, 0.f); VB = fmaxf(VB + dVB, 0.f);
        int mm = maskTab[i + 1];
        while (mm) {
            const int qq = __ffs(mm) - 1; mm &= mm - 1;
            float pay = wgtA * fmaxf(SA - ls_k[qq], 0.f) + wgtB * fmaxf(SB - ls_k[qq], 0.f);
            #pragma unroll
            for (int off = 32; off > 0; off >>= 1)
                pay += __shfl_down(pay, off, 64);
            if (tid == 0) atomicAdd(&acc[qq], pay);
        }
    }
}

__global__ void price_kernel(const float* __restrict__ x, const float* __restrict__ acc,
                             float* __restrict__ out) {
    const int q = threadIdx.x;
    if (q < NOPTS) {
        const float mat = x[q * 2];
        out[q] = acc[q] * (1.0f / (float)MPATHS) * expf((-0.025f * mat) / 360.0f);
    }
}

extern "C" void kernel_launch(void* const* d_in, const int* in_sizes, int n_in,
                              void* d_out, int out_size, void* d_ws, size_t ws_size,
                              hipStream_t stream)
{
    const float* x  = (const float*)d_in[0];
    const float* z  = (const float*)d_in[1];
    const float* z1 = (const float*)d_in[2];
    const float* W1 = (const float*)d_in[3];
    const float* b1 = (const float*)d_in[4];
    const float* W2 = (const float*)d_in[5];
    const float* b2 = (const float*)d_in[6];
    const float* Wo = (const float*)d_in[7];
    const float* bo = (const float*)d_in[8];

    char* ws = (char*)d_ws;
    float*    acc  = (float*)ws;                 // 128 B
    int*      flag = (int*)(ws + 256);
    int*      tbl  = (int*)(ws + 1024);          // 8.3 KB tables (incl. Minv)
    uint4*    w1f  = (uint4*)(ws + 16384);       // 16 KB
    uint4*    w2f  = (uint4*)(ws + 32768);       // 32 KB
    unsigned* wp1  = (unsigned*)(ws + 65536);    // 2 KB
    unsigned* wp2  = wp1 + 512;                  // 32 KB

    (void)hipMemsetAsync(acc, 0, NOPTS * sizeof(float), stream);
    pack_w<<<(512 + 8192 + 255) / 256, 256, 0, stream>>>(W1, W2, wp1, wp2);
    probe_mn<<<1, 64, 0, stream>>>(tbl);
    probe_k<<<512, 64, 0, stream>>>(tbl);
    finalize_verify<<<1, 64, 0, stream>>>(tbl, flag);
    build_frags<<<12, 256, 0, stream>>>(W1, b1, W2, tbl, w1f, w2f);

    const int gridS = (MPATHS + 63) / 64;    // 1563 blocks x 4 waves (net-per-wave)
    sde_mfma_w4<<<gridS, 256, 0, stream>>>(x, z, z1, b2, Wo, bo, tbl, w1f, w2f, flag, acc);
    const int gridF = (MPATHS + 127) / 128;  // 782 (fallback)
    sde_dot2<<<gridF, 64, 0, stream>>>(x, z, z1, b1, b2, Wo, bo,
                                       (const uint4*)wp1, (const uint4*)wp2, flag, acc);
    price_kernel<<<1, 64, 0, stream>>>(x, acc, (float*)d_out);
}

// Round 7
// 1567.371 us; speedup vs baseline: 1.0987x; 1.0014x over previous
//
#include <hip/hip_runtime.h>
#include <math.h>

#define MC      50000
#define MPATHS  100000
#define NSTEPS  180
#define NOPTS   32

typedef __attribute__((ext_vector_type(8))) short short8;
typedef __attribute__((ext_vector_type(4))) float float4v;
typedef __attribute__((ext_vector_type(4))) unsigned u32x4;
typedef _Float16 half2v __attribute__((ext_vector_type(2)));
typedef unsigned u32x32 __attribute__((ext_vector_type(32)));

// ---------- helpers ----------
static __device__ __forceinline__ unsigned bf16u(float x) {        // RNE
    unsigned u = __float_as_uint(x);
    return (u + 0x7fffu + ((u >> 16) & 1u)) >> 16;
}
static __device__ __forceinline__ float bf16val(float x) {
    return __uint_as_float(bf16u(x) << 16);
}
static __device__ __forceinline__ unsigned pkh2(float a, float b) { // f16 pair (fallback path)
    half2v h; h.x = (_Float16)a; h.y = (_Float16)b;
    return __builtin_bit_cast(unsigned, h);
}
static __device__ __forceinline__ unsigned pkrtz(float a, float b) {
    auto h = __builtin_amdgcn_cvt_pkrtz(a, b);
    return __builtin_bit_cast(unsigned, h);
}
static __device__ __forceinline__ float fdot2(unsigned w, unsigned h, float c) {
    return __builtin_amdgcn_fdot2(__builtin_bit_cast(half2v, w),
                                  __builtin_bit_cast(half2v, h), c, false);
}
static __device__ __forceinline__ short8 fr4(unsigned a, unsigned b,
                                             unsigned c, unsigned d) {
    union { unsigned u[4]; short8 s; } t;
    t.u[0] = a; t.u[1] = b; t.u[2] = c; t.u[3] = d;
    return t.s;
}
static __device__ __forceinline__ float4v mfma16(short8 a, short8 b, float4v c) {
    return __builtin_amdgcn_mfma_f32_16x16x32_bf16(a, b, c, 0, 0, 0);
}

// ws table region (ints): [0..511]=mA  [512..1023]=kA(kid->rank)
//                          [1024..1535]=nB  [1536..2047]=kB(kid->rank)
//                          [2048..2079]=Minv (k-rank -> W2 local column, fast path)

// ---------- probe 1: m-map (A) and n-map (B); trusts only C/D layout ----------
__global__ void probe_mn(int* tbl) {
    const int lane = threadIdx.x;
    for (int s = lane; s < 2048; s += 64) tbl[s] = 0;   // defaults (safe clamp later)
    const float4v z4 = {0.f, 0.f, 0.f, 0.f};
    for (int L = 0; L < 64; ++L)
        for (int j = 0; j < 8; ++j) {
            unsigned au[4] = {0u, 0u, 0u, 0u};
            if (lane == L) au[j >> 1] = 0x3F80u << (16 * (j & 1));
            short8 a = fr4(au[0], au[1], au[2], au[3]);
            short8 b = fr4(0x3F803F80u, 0x3F803F80u, 0x3F803F80u, 0x3F803F80u);
            float4v d = mfma16(a, b, z4);
            if ((lane & 15) == 0) {
                #pragma unroll
                for (int r = 0; r < 4; ++r)
                    if (d[r] != 0.0f) tbl[L * 8 + j] = (lane >> 4) * 4 + r;
            }
        }
    for (int L = 0; L < 64; ++L)
        for (int j = 0; j < 8; ++j) {
            unsigned bu[4] = {0u, 0u, 0u, 0u};
            if (lane == L) bu[j >> 1] = 0x3F80u << (16 * (j & 1));
            short8 a = fr4(0x3F803F80u, 0x3F803F80u, 0x3F803F80u, 0x3F803F80u);
            short8 b = fr4(bu[0], bu[1], bu[2], bu[3]);
            float4v d = mfma16(a, b, z4);
            if ((lane >> 4) == 0 && d[0] != 0.0f) tbl[1024 + L * 8 + j] = (lane & 15);
        }
}

// ---------- probe 2: k-equivalence classes between A-slots and B-slots ----------
__global__ void probe_k(int* tbl) {
    const int lane = threadIdx.x;
    const int sA = blockIdx.x;              // 0..511
    const float4v z4 = {0.f, 0.f, 0.f, 0.f};
    unsigned au[4] = {0u, 0u, 0u, 0u};
    if (lane == (sA >> 3)) au[(sA & 7) >> 1] = 0x3F80u << (16 * (sA & 1));
    short8 a = fr4(au[0], au[1], au[2], au[3]);
    int kid = -1;
    for (int sB = 0; sB < 512; ++sB) {
        unsigned bu[4] = {0u, 0u, 0u, 0u};
        const int LB = sB >> 3, jB = sB & 7;
        if (lane == LB) bu[jB >> 1] = 0x3F80u << (16 * (jB & 1));
        short8 b = fr4(bu[0], bu[1], bu[2], bu[3]);
        float4v d = mfma16(a, b, z4);
        bool hit = (d[0] != 0.f) | (d[1] != 0.f) | (d[2] != 0.f) | (d[3] != 0.f);
        if (__any(hit)) {
            if (kid < 0) kid = sB;
            if (lane == 0) tbl[1536 + sB] = kid;   // benign same-value races
        }
    }
    if (lane == 0) tbl[512 + sA] = (kid < 0) ? 0 : kid;
}

// ---------- probe 3: rank k-classes; verify layout stack + fast-path conditions ----------
// Fast path additionally requires (checked exactly):
//   (a) B n-map standard: nb(lane,j) == lane&15
//   (b) B k-ranks independent of lane&15 (function of (g=lane>>4, j) only)
//   (c) (g,j) -> rank bijective onto 0..31
// Then Minv[rank(g,j)] = 16*((j>>2)&1) + 4*g + 2*((j>>1)&1) + (j&1) re-indexes W2
// columns so layer-2's B fragment equals layer-1's packed D registers verbatim.
__global__ void finalize_verify(int* tbl, int* flag) {
    __shared__ int cnt[32];
    __shared__ int minv[32];
    const int lane = threadIdx.x;
    if (lane < 32) { cnt[lane] = 0; minv[lane] = 0; }
    int rA[8], rB[8];
    #pragma unroll
    for (int j = 0; j < 8; ++j) {
        const int s = lane * 8 + j;
        const int kidA = tbl[512 + s], kidB = tbl[1536 + s];
        int ra = 0, rb = 0;
        for (int u = 0; u < 512; ++u) {
            const int canon = (tbl[1536 + u] == u);
            ra += canon & (u < kidA);
            rb += canon & (u < kidB);
        }
        rA[j] = ra & 31; rB[j] = rb & 31;
    }
    __syncthreads();
    #pragma unroll
    for (int j = 0; j < 8; ++j) {
        tbl[512 + lane * 8 + j]  = rA[j];
        tbl[1536 + lane * 8 + j] = rB[j];
    }
    // verify: integer GEMM through discovered tables, exact compare
    unsigned au[4] = {0u, 0u, 0u, 0u}, bu[4] = {0u, 0u, 0u, 0u};
    #pragma unroll
    for (int j = 0; j < 8; ++j) {
        const int s = lane * 8 + j;
        const int m = tbl[s] & 15, ka = rA[j];
        const int n = tbl[1024 + s] & 15, kb = rB[j];
        const int fv = ((m * 7 + ka * 3) % 5) - 2;
        const int gv = ((kb * 5 + n * 11) % 7) - 3;
        au[j >> 1] |= bf16u((float)fv) << (16 * (j & 1));
        bu[j >> 1] |= bf16u((float)gv) << (16 * (j & 1));
    }
    const float4v z4 = {0.f, 0.f, 0.f, 0.f};
    float4v d = mfma16(fr4(au[0], au[1], au[2], au[3]),
                       fr4(bu[0], bu[1], bu[2], bu[3]), z4);
    const int col = lane & 15;
    bool ok = true;
    #pragma unroll
    for (int r = 0; r < 4; ++r) {
        const int row = (lane >> 4) * 4 + r;
        int ref = 0;
        for (int k = 0; k < 32; ++k)
            ref += (((row * 7 + k * 3) % 5) - 2) * (((k * 5 + col * 11) % 7) - 3);
        ok = ok && (d[r] == (float)ref);
    }
    // fast-path conditions (a),(b)
    bool okf = ok;
    #pragma unroll
    for (int j = 0; j < 8; ++j) {
        okf = okf && ((tbl[1024 + lane * 8 + j] & 15) == (lane & 15));
        const int ref = __shfl(rB[j], lane & 48, 64);
        okf = okf && (rB[j] == ref);
    }
    // (c) bijectivity + Minv build (c==0 lanes cover all 32 (g,j) positions)
    if ((lane & 15) == 0) {
        const int g = lane >> 4;
        #pragma unroll
        for (int j = 0; j < 8; ++j) {
            atomicAdd(&cnt[rB[j]], 1);
            minv[rB[j]] = 16 * ((j >> 2) & 1) + 4 * g + 2 * ((j >> 1) & 1) + (j & 1);
        }
    }
    __syncthreads();
    if (lane < 32) {
        okf = okf && (cnt[lane] == 1);
        tbl[2048 + lane] = minv[lane];
    }
    const bool allok = __all(okf);
    if (lane == 0) *flag = allok ? 1 : 0;
}

// ---------- build W1/W2 A-fragment tables (after verify tables final) ----------
// W2 columns permuted by Minv so layer-2 B-frag == layer-1 packed D registers.
__global__ void build_frags(const float* __restrict__ W1, const float* __restrict__ b1,
                            const float* __restrict__ W2, const int* __restrict__ tbl,
                            uint4* __restrict__ w1f, uint4* __restrict__ w2f) {
    const int t = blockIdx.x * 256 + threadIdx.x;   // 0..3071
    if (t >= 3072) return;
    const int lane = t & 63, frag = t >> 6;
    const float rateB = bf16val(0.025f);
    unsigned u[4] = {0u, 0u, 0u, 0u};
    if (frag < 16) {            // W1: net=frag>>2, mt=frag&3 ; k 0..5 hi, 6..11 lo-residual
        const int net = frag >> 2, mt = frag & 3;
        #pragma unroll
        for (int j = 0; j < 8; ++j) {
            const int s = lane * 8 + j;
            const int m = tbl[s] & 15, k = tbl[512 + s] & 31;
            unsigned bits = 0u;
            if (k < 12) {
                const int kk = (k < 6) ? k : k - 6;
                const int M = net * 64 + 16 * mt + m;
                float v;
                if (kk == 0)                 v = W1[M * 4 + 0];
                else if (kk == 1 || kk == 4) v = W1[M * 4 + 1];
                else if (kk == 2 || kk == 5) v = W1[M * 4 + 2];
                else                         v = W1[M * 4 + 3] + b1[M] / rateB;
                bits = (k < 6) ? bf16u(v) : bf16u(v - bf16val(v));
            }
            u[j >> 1] |= bits << (16 * (j & 1));
        }
        w1f[frag * 64 + lane] = make_uint4(u[0], u[1], u[2], u[3]);
    } else {                    // W2: f2=frag-16: net=f2>>3, mt=(f2>>1)&3, kc=f2&1
        const int f2 = frag - 16;
        const int net = f2 >> 3, mt = (f2 >> 1) & 3, kc = f2 & 1;
        #pragma unroll
        for (int j = 0; j < 8; ++j) {
            const int s = lane * 8 + j;
            const int m = tbl[s] & 15, k = tbl[512 + s] & 31;
            const float v = W2[(net * 64 + 16 * mt + m) * 64 + 32 * kc + tbl[2048 + k]];
            u[j >> 1] |= bf16u(v) << (16 * (j & 1));
        }
        w2f[f2 * 64 + lane] = make_uint4(u[0], u[1], u[2], u[3]);
    }
}

// ---------- main MFMA path-sim: 4 waves/block, 1 net per wave, LDS-free B1 ----------
// Round-6 structure (best verified: 1470 us) + operand-tuple hygiene:
// all MFMA operands live in native ext_vector registers (u32x4/short8 via
// bit_cast, no unions, no struct-uint4 round trips). The perm-pack results are
// written directly into the vector components that form the layer-2 B operand,
// so the pack IS the operand construction -- targets the ~500 v_mov/step the
// round-6 counters implied (VALUBusy 65% with only ~360 essential VALU insts).
__global__ __launch_bounds__(256, 3)
void sde_mfma_w4(const float* __restrict__ x, const float* __restrict__ z,
                 const float* __restrict__ z1, const float* __restrict__ b2,
                 const float* __restrict__ Wo, const float* __restrict__ bo,
                 const int* __restrict__ tbl, const uint4* __restrict__ w1f,
                 const uint4* __restrict__ w2f, const int* __restrict__ flag,
                 float* __restrict__ acc)
{
    if (*flag != 1) return;
    __shared__ __align__(16) float wo_s[256];
    __shared__ __align__(16) float b2_s[256];
    __shared__ float dxch[2][4][64];
    __shared__ float ls_k[NOPTS];
    __shared__ int   maskTab[NSTEPS + 4];

    const int tid = threadIdx.x;
    const int wv = tid >> 6, lane = tid & 63;   // wv == net index
    const int q = lane >> 4, c = lane & 15;

    for (int j = tid; j < 256; j += 256) { wo_s[j] = Wo[j]; b2_s[j] = b2[j]; }
    for (int j = tid; j < NSTEPS + 4; j += 256) maskTab[j] = 0;
    if (tid < NOPTS) ls_k[tid] = x[2 * tid + 1];
    __syncthreads();
    if (tid < NOPTS) atomicOr(&maskTab[(int)x[2 * tid]], 1 << tid);
    __syncthreads();

    // per-lane B1 assembly tables from discovered k-map
    // rows: 0=t 1=S 2=V 3=rate 4=Sres 5=Vres 6=zero
    const unsigned rate16 = bf16u(0.025f);
    unsigned selAB[4], dynM[4], cU[4], mT[4];
    {
        int rowj[8];
        #pragma unroll
        for (int j = 0; j < 8; ++j) {
            const int kb = tbl[1536 + lane * 8 + j] & 31;
            rowj[j] = (kb < 6) ? kb : ((kb < 12) ? kb - 6 : 6);
        }
        #pragma unroll
        for (int w = 0; w < 4; ++w) {
            unsigned s = 0, d = 0, cu = 0, mt_ = 0;
            #pragma unroll
            for (int h = 0; h < 2; ++h) {
                const int r = rowj[2 * w + h];
                unsigned hs = 0x0504u, hd = 0u, hcu = 0u, hmt = 0u;
                if      (r == 1) { hs = 0x0504u; hd = 0xFFFFu; }   // S  = Ap lo16
                else if (r == 2) { hs = 0x0706u; hd = 0xFFFFu; }   // V  = Ap hi16
                else if (r == 4) { hs = 0x0100u; hd = 0xFFFFu; }   // Sr = Bp lo16
                else if (r == 5) { hs = 0x0302u; hd = 0xFFFFu; }   // Vr = Bp hi16
                else if (r == 0) { hmt = 0xFFFFu; }                // t (per-step)
                else if (r == 3) { hcu = rate16; }                 // rate const
                // r==6: zero
                s  |= hs  << (16 * h); d   |= hd  << (16 * h);
                cu |= hcu << (16 * h); mt_ |= hmt << (16 * h);
            }
            selAB[w] = s; dynM[w] = d; cU[w] = cu; mT[w] = mt_;
        }
    }

    const int p_ = blockIdx.x * 64 + lane;      // 64 paths per block
    const float wgt = (p_ < MPATHS) ? 1.0f : 0.0f;
    int pc = (p_ < MPATHS) ? p_ : (MPATHS - 1);
    float sgn = 1.0f; int row_ = pc;
    if (pc >= MC) { sgn = -1.0f; row_ -= MC; }
    const float* __restrict__ zrow  = z  + (size_t)row_ * NSTEPS;
    const float* __restrict__ z1row = z1 + (size_t)row_ * NSTEPS;

    const float hh = 1.0f / 360.0f, sqh = sqrtf(hh);
    const float s75 = 0.86602540378443864676f;
    const float bon = bo[wv];

    // hoisted A fragments for this wave's net, as native 128-bit vectors
    const u32x4* __restrict__ w1v = (const u32x4*)w1f;
    const u32x4* __restrict__ w2v = (const u32x4*)w2f;
    u32x4 a1v[4], a2v[8];
    #pragma unroll
    for (int mt = 0; mt < 4; ++mt) {
        a1v[mt]         = w1v[(wv * 4 + mt) * 64 + lane];
        a2v[2 * mt]     = w2v[((wv * 4 + mt) * 2 + 0) * 64 + lane];
        a2v[2 * mt + 1] = w2v[((wv * 4 + mt) * 2 + 1) * 64 + lane];
    }
    // hoisted per-thread-constant epilogue operands (were per-step LDS reads)
    float4  wo4r[4];
    float4v c4r[4];
    #pragma unroll
    for (int mt = 0; mt < 4; ++mt) {
        wo4r[mt] = *(const float4*)&wo_s[wv * 64 + 16 * mt + 4 * q];
        c4r[mt]  = *(const float4v*)&b2_s[wv * 64 + 16 * mt + 4 * q];
    }

    float S = 100.0f, V = 0.04f;

    // z/z1 chunk state: 4 steps per chunk, prefetch one chunk ahead
    const bool needZ  = (wv == 1) | (wv == 3);
    const bool needZ1 = (wv == 3);
    float4 zc = {0.f, 0.f, 0.f, 0.f}, z1c = {0.f, 0.f, 0.f, 0.f};
    float4 zn = zc, z1n = z1c;
    if (needZ)  zc  = *(const float4*)(zrow);
    if (needZ1) z1c = *(const float4*)(z1row);

    #pragma unroll 1
    for (int ch = 0; ch < NSTEPS / 4; ++ch) {
        // prefetch next chunk (latency hidden under this chunk's 4 steps)
        if (ch + 1 < NSTEPS / 4) {
            if (needZ)  zn  = *(const float4*)(zrow  + 4 * (ch + 1));
            if (needZ1) z1n = *(const float4*)(z1row + 4 * (ch + 1));
        }
        #pragma unroll
        for (int ii = 0; ii < 4; ++ii) {
            const int i = 4 * ch + ii;
            const float zz  = (ii == 0) ? zc.x  : (ii == 1) ? zc.y  : (ii == 2) ? zc.z  : zc.w;
            const float zz1 = (ii == 0) ? z1c.x : (ii == 1) ? z1c.y : (ii == 2) ? z1c.z : z1c.w;
            // per-wave multiplier of this net's output
            float mult;
            if      (wv == 1) mult = sqh * (sgn * zz);
            else if (wv == 3) mult = sqh * (sgn * (-0.5f * zz + s75 * zz1));
            else              mult = hh;

            const float t = (float)i * hh;
            const unsigned tB = bf16u(t);
            const unsigned tB2 = tB | (tB << 16);
            unsigned UW[4];
            #pragma unroll
            for (int w = 0; w < 4; ++w) UW[w] = cU[w] | (mT[w] & tB2);

            // per-lane packed state words (own path)
            const unsigned Shu = bf16u(S), Vhu = bf16u(V);
            const unsigned PA = Shu | (Vhu << 16);
            const float Sr = S - __uint_as_float(Shu << 16);
            const float Vr = V - __uint_as_float(Vhu << 16);
            const unsigned PB = __builtin_amdgcn_perm(__float_as_uint(Vr),
                                                      __float_as_uint(Sr), 0x07060302u);

            float part[4] = {0.f, 0.f, 0.f, 0.f};
            #pragma unroll
            for (int nt = 0; nt < 4; ++nt) {
                const int a = (nt << 6) | (c << 2);
                const unsigned Ap = (unsigned)__builtin_amdgcn_ds_bpermute(a, (int)PA);
                const unsigned Bp = (unsigned)__builtin_amdgcn_ds_bpermute(a, (int)PB);
                // B1 built directly in its vector register tuple
                u32x4 b1v;
                b1v.x = (__builtin_amdgcn_perm(Ap, Bp, selAB[0]) & dynM[0]) | UW[0];
                b1v.y = (__builtin_amdgcn_perm(Ap, Bp, selAB[1]) & dynM[1]) | UW[1];
                b1v.z = (__builtin_amdgcn_perm(Ap, Bp, selAB[2]) & dynM[2]) | UW[2];
                b1v.w = (__builtin_amdgcn_perm(Ap, Bp, selAB[3]) & dynM[3]) | UW[3];
                const short8 B1s = __builtin_bit_cast(short8, b1v);

                // ---- layer 1 MFMA -> relu -> pack straight into L2-B tuples ----
                const float4v z4 = {0.f, 0.f, 0.f, 0.f};
                u32x4 bk0, bk1;
                #pragma unroll
                for (int mt = 0; mt < 4; ++mt) {
                    float4v d = mfma16(__builtin_bit_cast(short8, a1v[mt]), B1s, z4);
                    const unsigned r0 = __float_as_uint(fmaxf(d[0], 0.f));
                    const unsigned r1 = __float_as_uint(fmaxf(d[1], 0.f));
                    const unsigned r2 = __float_as_uint(fmaxf(d[2], 0.f));
                    const unsigned r3 = __float_as_uint(fmaxf(d[3], 0.f));
                    const unsigned plo = __builtin_amdgcn_perm(r1, r0, 0x07060302u);
                    const unsigned phi = __builtin_amdgcn_perm(r3, r2, 0x07060302u);
                    if      (mt == 0) { bk0.x = plo; bk0.y = phi; }
                    else if (mt == 1) { bk0.z = plo; bk0.w = phi; }
                    else if (mt == 2) { bk1.x = plo; bk1.y = phi; }
                    else              { bk1.z = plo; bk1.w = phi; }
                }
                const short8 Bk0 = __builtin_bit_cast(short8, bk0);
                const short8 Bk1 = __builtin_bit_cast(short8, bk1);
                // ---- layer 2 MFMA (bias in C operand) + fused epilogue ----
                #pragma unroll
                for (int mt = 0; mt < 4; ++mt) {
                    float4v d = mfma16(__builtin_bit_cast(short8, a2v[2 * mt]), Bk0, c4r[mt]);
                    d = mfma16(__builtin_bit_cast(short8, a2v[2 * mt + 1]), Bk1, d);
                    part[nt] += wo4r[mt].x * fmaxf(d[0], 0.f)
                              + wo4r[mt].y * fmaxf(d[1], 0.f)
                              + wo4r[mt].z * fmaxf(d[2], 0.f)
                              + wo4r[mt].w * fmaxf(d[3], 0.f);
                }
            }
            #pragma unroll
            for (int nt = 0; nt < 4; ++nt) {
                float s2 = part[nt];
                s2 += __shfl_xor(s2, 16, 64);
                s2 += __shfl_xor(s2, 32, 64);
                part[nt] = s2;
            }
            float o = (q == 0) ? part[0] : (q == 1) ? part[1] : (q == 2) ? part[2] : part[3];
            o += bon;

            // exchange: each wave contributes o*mult; dS = w0+w1, dV = w2+w3
            dxch[i & 1][wv][lane] = o * mult;
            __syncthreads();
            const float dS = dxch[i & 1][0][lane] + dxch[i & 1][1][lane];
            const float dV = dxch[i & 1][2][lane] + dxch[i & 1][3][lane];
            S = fmaxf(S + dS, 0.0f);
            V = fmaxf(V + dV, 0.0f);

            if (wv == 0) {
                int mm = maskTab[i + 1];
                while (mm) {
                    const int qq = __ffs(mm) - 1; mm &= mm - 1;
                    float pay = wgt * fmaxf(S - ls_k[qq], 0.0f);
                    #pragma unroll
                    for (int off = 32; off > 0; off >>= 1)
                        pay += __shfl_down(pay, off, 64);
                    if (lane == 0) atomicAdd(&acc[qq], pay);
                }
            }
        }
        zc = zn; z1c = z1n;
    }
}

// ---------- fallback: round-9 dot2 kernel (proven), gated on !flag ----------
__global__ void pack_w(const float* __restrict__ W1, const float* __restrict__ W2,
                       unsigned* __restrict__ wp1, unsigned* __restrict__ wp2) {
    int i = blockIdx.x * 256 + threadIdx.x;
    if (i < 512)              wp1[i] = pkh2(W1[2 * i], W1[2 * i + 1]);
    else if (i < 512 + 8192) { int k = i - 512; wp2[k] = pkh2(W2[2 * k], W2[2 * k + 1]); }
}

__global__ __launch_bounds__(64, 2)
void sde_dot2(const float* __restrict__ x, const float* __restrict__ z,
              const float* __restrict__ z1, const float* __restrict__ b1,
              const float* __restrict__ b2, const float* __restrict__ Wo,
              const float* __restrict__ bo, const uint4* __restrict__ wp1,
              const uint4* __restrict__ wp2, const int* __restrict__ flag,
              float* __restrict__ acc)
{
    if (*flag == 1) return;
    __shared__ __align__(16) uint4 wlds[2176];
    __shared__ float ls_k[NOPTS];
    __shared__ int   maskTab[NSTEPS + 4];
    const int tid = threadIdx.x;
    for (int j = tid; j < 2176; j += 64) wlds[j] = (j < 128) ? wp1[j] : wp2[j - 128];
    for (int jj = tid; jj < NSTEPS + 4; jj += 64) maskTab[jj] = 0;
    if (tid < NOPTS) ls_k[tid] = x[2 * tid + 1];
    __syncthreads();
    if (tid < NOPTS) atomicOr(&maskTab[(int)x[2 * tid]], 1 << tid);
    __syncthreads();
    const int pA = blockIdx.x * 128 + tid, pB = pA + 64;
    const float wgtA = (pA < MPATHS) ? 1.0f : 0.0f;
    const float wgtB = (pB < MPATHS) ? 1.0f : 0.0f;
    int pcA = (pA < MPATHS) ? pA : (MPATHS - 1);
    int pcB = (pB < MPATHS) ? pB : (MPATHS - 1);
    float sgnA = 1.0f, sgnB = 1.0f; int rowA = pcA, rowB = pcB;
    if (pcA >= MC) { sgnA = -1.0f; rowA -= MC; }
    if (pcB >= MC) { sgnB = -1.0f; rowB -= MC; }
    const float* __restrict__ zA  = z  + (size_t)rowA * NSTEPS;
    const float* __restrict__ z1A = z1 + (size_t)rowA * NSTEPS;
    const float* __restrict__ zB  = z  + (size_t)rowB * NSTEPS;
    const float* __restrict__ z1B = z1 + (size_t)rowB * NSTEPS;
    const float hh = 1.0f / 360.0f, sqh = sqrtf(hh);
    const float s75 = 0.86602540378443864676f, rate = 0.025f;
    float SA = 100.0f, VA = 0.04f, SB = 100.0f, VB = 0.04f;
    #pragma unroll 1
    for (int i = 0; i < NSTEPS; ++i) {
        const float zcrA = zA[i], z1rA = z1A[i], zcrB = zB[i], z1rB = z1B[i];
        const float dWA = sqh * (sgnA * zcrA);
        const float dW1A = sqh * (sgnA * (-0.5f * zcrA + s75 * z1rA));
        const float dWB = sqh * (sgnB * zcrB);
        const float dW1B = sqh * (sgnB * (-0.5f * zcrB + s75 * z1rB));
        const float t = (float)i * hh;
        const unsigned inA01 = pkrtz(t, SA), inA23 = pkrtz(VA, rate);
        const unsigned inB01 = pkrtz(t, SB), inB23 = pkrtz(VB, rate);
        float dSA = 0.f, dVA = 0.f, dSB = 0.f, dVB = 0.f;
        #pragma unroll 1
        for (int net = 0; net < 4; ++net) {
            const float* __restrict__ b1n = b1 + net * 64;
            const float* __restrict__ b2n = b2 + net * 64;
            const float* __restrict__ won = Wo + net * 64;
            const uint4* __restrict__ wl1 = &wlds[net * 32];
            const uint4* __restrict__ wl2 = &wlds[128 + net * 512];
            u32x32 hA, hB;
            #pragma unroll
            for (int u = 0; u < 64; u += 2) {
                const uint4 wv = wl1[u >> 1];
                const float bb0 = b1n[u], bb1 = b1n[u + 1];
                float a0 = fdot2(wv.x, inA01, bb0); a0 = fdot2(wv.y, inA23, a0);
                float a1 = fdot2(wv.z, inA01, bb1); a1 = fdot2(wv.w, inA23, a1);
                float c0 = fdot2(wv.x, inB01, bb0); c0 = fdot2(wv.y, inB23, c0);
                float c1 = fdot2(wv.z, inB01, bb1); c1 = fdot2(wv.w, inB23, c1);
                hA[u >> 1] = pkrtz(fmaxf(a0, 0.f), fmaxf(a1, 0.f));
                hB[u >> 1] = pkrtz(fmaxf(c0, 0.f), fmaxf(c1, 0.f));
            }
            float outA = bo[net], outB = outA;
            #pragma unroll 1
            for (int j = 0; j < 64; j += 4) {
                const uint4* __restrict__ r0 = wl2 + (j + 0) * 8;
                const uint4* __restrict__ r1 = wl2 + (j + 1) * 8;
                const uint4* __restrict__ r2 = wl2 + (j + 2) * 8;
                const uint4* __restrict__ r3 = wl2 + (j + 3) * 8;
                float a0 = b2n[j], a1 = b2n[j + 1], a2 = b2n[j + 2], a3 = b2n[j + 3];
                float c0 = a0, c1 = a1, c2 = a2, c3 = a3;
                #pragma unroll
                for (int kk = 0; kk < 8; ++kk) {
                    const uint4 w0 = r0[kk], w1 = r1[kk], w2 = r2[kk], w3 = r3[kk];
                    const unsigned hA0 = hA[4 * kk], hA1 = hA[4 * kk + 1];
                    const unsigned hA2 = hA[4 * kk + 2], hA3 = hA[4 * kk + 3];
                    const unsigned hB0 = hB[4 * kk], hB1 = hB[4 * kk + 1];
                    const unsigned hB2 = hB[4 * kk + 2], hB3 = hB[4 * kk + 3];
                    a0 = fdot2(w0.x, hA0, a0); a0 = fdot2(w0.y, hA1, a0);
                    a0 = fdot2(w0.z, hA2, a0); a0 = fdot2(w0.w, hA3, a0);
                    a1 = fdot2(w1.x, hA0, a1); a1 = fdot2(w1.y, hA1, a1);
                    a1 = fdot2(w1.z, hA2, a1); a1 = fdot2(w1.w, hA3, a1);
                    a2 = fdot2(w2.x, hA0, a2); a2 = fdot2(w2.y, hA1, a2);
                    a2 = fdot2(w2.z, hA2, a2); a2 = fdot2(w2.w, hA3, a2);
                    a3 = fdot2(w3.x, hA0, a3); a3 = fdot2(w3.y, hA1, a3);
                    a3 = fdot2(w3.z, hA2, a3); a3 = fdot2(w3.w, hA3, a3);
                    c0 = fdot2(w0.x, hB0, c0); c0 = fdot2(w0.y, hB1, c0);
                    c0 = fdot2(w0.z, hB2, c0); c0 = fdot2(w0.w, hB3, c0);
                    c1 = fdot2(w1.x, hB0, c1); c1 = fdot2(w1.y, hB1, c1);
                    c1 = fdot2(w1.z, hB2, c1); c1 = fdot2(w1.w, hB3, c1);
                    c2 = fdot2(w2.x, hB0, c2); c2 = fdot2(w2.y, hB1, c2);
                    c2 = fdot2(w2.z, hB2, c2); c2 = fdot2(w2.w, hB3, c2);
                    c3 = fdot2(w3.x, hB0, c3); c3 = fdot2(w3.y, hB1, c3);
                    c3 = fdot2(w3.z, hB2, c3); c3 = fdot2(w3.w, hB3, c3);
                }
                const float wo0 = won[j], wo1 = won[j + 1];
                const float wo2 = won[j + 2], wo3 = won[j + 3];
                outA = fmaf(wo0, fmaxf(a0, 0.f), outA); outA = fmaf(wo1, fmaxf(a1, 0.f), outA);
                outA = fmaf(wo2, fmaxf(a2, 0.f), outA); outA = fmaf(wo3, fmaxf(a3, 0.f), outA);
                outB = fmaf(wo0, fmaxf(c0, 0.f), outB); outB = fmaf(wo1, fmaxf(c1, 0.f), outB);
                outB = fmaf(wo2, fmaxf(c2, 0.f), outB); outB = fmaf(wo3, fmaxf(c3, 0.f), outB);
            }
            const float msA = (net == 0) ? hh : (net == 1) ? dWA  : 0.0f;
            const float mvA = (net == 2) ? hh : (net == 3) ? dW1A : 0.0f;
            const float msB = (net == 0) ? hh : (net == 1) ? dWB  : 0.0f;
            const float mvB = (net == 2) ? hh : (net == 3) ? dW1B : 0.0f;
            dSA = fmaf(outA, msA, dSA); dVA = fmaf(outA, mvA, dVA);
            dSB = fmaf(outB, msB, dSB); dVB = fmaf(outB, mvB, dVB);
        }
        SA = fmaxf(SA + dSA, 0.f); VA = fmaxf(VA + dVA, 0.f);
        SB = fmaxf(SB + dSB, 0.f); VB = fmaxf(VB + dVB, 0.f);
        int mm = maskTab[i + 1];
        while (mm) {
            const int qq = __ffs(mm) - 1; mm &= mm - 1;
            float pay = wgtA * fmaxf(SA - ls_k[qq], 0.f) + wgtB * fmaxf(SB - ls_k[qq], 0.f);
            #pragma unroll
            for (int off = 32; off > 0; off >>= 1)
                pay += __shfl_down(pay, off, 64);
            if (tid == 0) atomicAdd(&acc[qq], pay);
        }
    }
}

__global__ void price_kernel(const float* __restrict__ x, const float* __restrict__ acc,
                             float* __restrict__ out) {
    const int q = threadIdx.x;
    if (q < NOPTS) {
        const float mat = x[q * 2];
        out[q] = acc[q] * (1.0f / (float)MPATHS) * expf((-0.025f * mat) / 360.0f);
    }
}

extern "C" void kernel_launch(void* const* d_in, const int* in_sizes, int n_in,
                              void* d_out, int out_size, void* d_ws, size_t ws_size,
                              hipStream_t stream)
{
    const float* x  = (const float*)d_in[0];
    const float* z  = (const float*)d_in[1];
    const float* z1 = (const float*)d_in[2];
    const float* W1 = (const float*)d_in[3];
    const float* b1 = (const float*)d_in[4];
    const float* W2 = (const float*)d_in[5];
    const float* b2 = (const float*)d_in[6];
    const float* Wo = (const float*)d_in[7];
    const float* bo = (const float*)d_in[8];

    char* ws = (char*)d_ws;
    float*    acc  = (float*)ws;                 // 128 B
    int*      flag = (int*)(ws + 256);
    int*      tbl  = (int*)(ws + 1024);          // 8.3 KB tables (incl. Minv)
    uint4*    w1f  = (uint4*)(ws + 16384);       // 16 KB
    uint4*    w2f  = (uint4*)(ws + 32768);       // 32 KB
    unsigned* wp1  = (unsigned*)(ws + 65536);    // 2 KB
    unsigned* wp2  = wp1 + 512;                  // 32 KB

    (void)hipMemsetAsync(acc, 0, NOPTS * sizeof(float), stream);
    pack_w<<<(512 + 8192 + 255) / 256, 256, 0, stream>>>(W1, W2, wp1, wp2);
    probe_mn<<<1, 64, 0, stream>>>(tbl);
    probe_k<<<512, 64, 0, stream>>>(tbl);
    finalize_verify<<<1, 64, 0, stream>>>(tbl, flag);
    build_frags<<<12, 256, 0, stream>>>(W1, b1, W2, tbl, w1f, w2f);

    const int gridS = (MPATHS + 63) / 64;    // 1563 blocks x 4 waves (net-per-wave)
    sde_mfma_w4<<<gridS, 256, 0, stream>>>(x, z, z1, b2, Wo, bo, tbl, w1f, w2f, flag, acc);
    const int gridF = (MPATHS + 127) / 128;  // 782 (fallback)
    sde_dot2<<<gridF, 64, 0, stream>>>(x, z, z1, b1, b2, Wo, bo,
                                       (const uint4*)wp1, (const uint4*)wp2, flag, acc);
    price_kernel<<<1, 64, 0, stream>>>(x, acc, (float*)d_out);
}

// Round 8
// 1488.660 us; speedup vs baseline: 1.1568x; 1.0529x over previous
//
#include <hip/hip_runtime.h>
#include <math.h>

#define MC      50000
#define MPATHS  100000
#define NSTEPS  180
#define NOPTS   32

typedef __attribute__((ext_vector_type(8))) short short8;
typedef __attribute__((ext_vector_type(4))) float float4v;
typedef __attribute__((ext_vector_type(4))) unsigned u32x4;
typedef _Float16 half2v __attribute__((ext_vector_type(2)));
typedef unsigned u32x32 __attribute__((ext_vector_type(32)));

// ---------- helpers ----------
static __device__ __forceinline__ unsigned bf16u(float x) {        // RNE
    unsigned u = __float_as_uint(x);
    return (u + 0x7fffu + ((u >> 16) & 1u)) >> 16;
}
static __device__ __forceinline__ float bf16val(float x) {
    return __uint_as_float(bf16u(x) << 16);
}
static __device__ __forceinline__ unsigned pkh2(float a, float b) { // f16 pair (fallback path)
    half2v h; h.x = (_Float16)a; h.y = (_Float16)b;
    return __builtin_bit_cast(unsigned, h);
}
static __device__ __forceinline__ unsigned pkrtz(float a, float b) {
    auto h = __builtin_amdgcn_cvt_pkrtz(a, b);
    return __builtin_bit_cast(unsigned, h);
}
static __device__ __forceinline__ float fdot2(unsigned w, unsigned h, float c) {
    return __builtin_amdgcn_fdot2(__builtin_bit_cast(half2v, w),
                                  __builtin_bit_cast(half2v, h), c, false);
}
static __device__ __forceinline__ short8 fr4(unsigned a, unsigned b,
                                             unsigned c, unsigned d) {
    union { unsigned u[4]; short8 s; } t;
    t.u[0] = a; t.u[1] = b; t.u[2] = c; t.u[3] = d;
    return t.s;
}
static __device__ __forceinline__ float4v mfma16(short8 a, short8 b, float4v c) {
    return __builtin_amdgcn_mfma_f32_16x16x32_bf16(a, b, c, 0, 0, 0);
}

// ws table region (ints): [0..511]=mA  [512..1023]=kA(kid->rank)
//                          [1024..1535]=nB  [1536..2047]=kB(kid->rank)
//                          [2048..2079]=Minv (k-rank -> W2 local column, fast path)

// ---------- probe 1: m-map (A) and n-map (B); trusts only C/D layout ----------
__global__ void probe_mn(int* tbl) {
    const int lane = threadIdx.x;
    for (int s = lane; s < 2048; s += 64) tbl[s] = 0;   // defaults (safe clamp later)
    const float4v z4 = {0.f, 0.f, 0.f, 0.f};
    for (int L = 0; L < 64; ++L)
        for (int j = 0; j < 8; ++j) {
            unsigned au[4] = {0u, 0u, 0u, 0u};
            if (lane == L) au[j >> 1] = 0x3F80u << (16 * (j & 1));
            short8 a = fr4(au[0], au[1], au[2], au[3]);
            short8 b = fr4(0x3F803F80u, 0x3F803F80u, 0x3F803F80u, 0x3F803F80u);
            float4v d = mfma16(a, b, z4);
            if ((lane & 15) == 0) {
                #pragma unroll
                for (int r = 0; r < 4; ++r)
                    if (d[r] != 0.0f) tbl[L * 8 + j] = (lane >> 4) * 4 + r;
            }
        }
    for (int L = 0; L < 64; ++L)
        for (int j = 0; j < 8; ++j) {
            unsigned bu[4] = {0u, 0u, 0u, 0u};
            if (lane == L) bu[j >> 1] = 0x3F80u << (16 * (j & 1));
            short8 a = fr4(0x3F803F80u, 0x3F803F80u, 0x3F803F80u, 0x3F803F80u);
            short8 b = fr4(bu[0], bu[1], bu[2], bu[3]);
            float4v d = mfma16(a, b, z4);
            if ((lane >> 4) == 0 && d[0] != 0.0f) tbl[1024 + L * 8 + j] = (lane & 15);
        }
}

// ---------- probe 2: k-equivalence classes between A-slots and B-slots ----------
__global__ void probe_k(int* tbl) {
    const int lane = threadIdx.x;
    const int sA = blockIdx.x;              // 0..511
    const float4v z4 = {0.f, 0.f, 0.f, 0.f};
    unsigned au[4] = {0u, 0u, 0u, 0u};
    if (lane == (sA >> 3)) au[(sA & 7) >> 1] = 0x3F80u << (16 * (sA & 1));
    short8 a = fr4(au[0], au[1], au[2], au[3]);
    int kid = -1;
    for (int sB = 0; sB < 512; ++sB) {
        unsigned bu[4] = {0u, 0u, 0u, 0u};
        const int LB = sB >> 3, jB = sB & 7;
        if (lane == LB) bu[jB >> 1] = 0x3F80u << (16 * (jB & 1));
        short8 b = fr4(bu[0], bu[1], bu[2], bu[3]);
        float4v d = mfma16(a, b, z4);
        bool hit = (d[0] != 0.f) | (d[1] != 0.f) | (d[2] != 0.f) | (d[3] != 0.f);
        if (__any(hit)) {
            if (kid < 0) kid = sB;
            if (lane == 0) tbl[1536 + sB] = kid;   // benign same-value races
        }
    }
    if (lane == 0) tbl[512 + sA] = (kid < 0) ? 0 : kid;
}

// ---------- probe 3: rank k-classes; verify layout stack + fast-path conditions ----------
// Fast path additionally requires (checked exactly):
//   (a) B n-map standard: nb(lane,j) == lane&15
//   (b) B k-ranks independent of lane&15 (function of (g=lane>>4, j) only)
//   (c) (g,j) -> rank bijective onto 0..31
// Then Minv[rank(g,j)] = 16*((j>>2)&1) + 4*g + 2*((j>>1)&1) + (j&1) re-indexes W2
// columns so layer-2's B fragment equals layer-1's packed D registers verbatim.
// The same identity chains to the OUTPUT layer: relu(L2-D) perm-packed feeds a
// third MFMA whose A = Wo (replicated rows, Minv-permuted columns).
__global__ void finalize_verify(int* tbl, int* flag) {
    __shared__ int cnt[32];
    __shared__ int minv[32];
    const int lane = threadIdx.x;
    if (lane < 32) { cnt[lane] = 0; minv[lane] = 0; }
    int rA[8], rB[8];
    #pragma unroll
    for (int j = 0; j < 8; ++j) {
        const int s = lane * 8 + j;
        const int kidA = tbl[512 + s], kidB = tbl[1536 + s];
        int ra = 0, rb = 0;
        for (int u = 0; u < 512; ++u) {
            const int canon = (tbl[1536 + u] == u);
            ra += canon & (u < kidA);
            rb += canon & (u < kidB);
        }
        rA[j] = ra & 31; rB[j] = rb & 31;
    }
    __syncthreads();
    #pragma unroll
    for (int j = 0; j < 8; ++j) {
        tbl[512 + lane * 8 + j]  = rA[j];
        tbl[1536 + lane * 8 + j] = rB[j];
    }
    // verify: integer GEMM through discovered tables, exact compare
    unsigned au[4] = {0u, 0u, 0u, 0u}, bu[4] = {0u, 0u, 0u, 0u};
    #pragma unroll
    for (int j = 0; j < 8; ++j) {
        const int s = lane * 8 + j;
        const int m = tbl[s] & 15, ka = rA[j];
        const int n = tbl[1024 + s] & 15, kb = rB[j];
        const int fv = ((m * 7 + ka * 3) % 5) - 2;
        const int gv = ((kb * 5 + n * 11) % 7) - 3;
        au[j >> 1] |= bf16u((float)fv) << (16 * (j & 1));
        bu[j >> 1] |= bf16u((float)gv) << (16 * (j & 1));
    }
    const float4v z4 = {0.f, 0.f, 0.f, 0.f};
    float4v d = mfma16(fr4(au[0], au[1], au[2], au[3]),
                       fr4(bu[0], bu[1], bu[2], bu[3]), z4);
    const int col = lane & 15;
    bool ok = true;
    #pragma unroll
    for (int r = 0; r < 4; ++r) {
        const int row = (lane >> 4) * 4 + r;
        int ref = 0;
        for (int k = 0; k < 32; ++k)
            ref += (((row * 7 + k * 3) % 5) - 2) * (((k * 5 + col * 11) % 7) - 3);
        ok = ok && (d[r] == (float)ref);
    }
    // fast-path conditions (a),(b)
    bool okf = ok;
    #pragma unroll
    for (int j = 0; j < 8; ++j) {
        okf = okf && ((tbl[1024 + lane * 8 + j] & 15) == (lane & 15));
        const int ref = __shfl(rB[j], lane & 48, 64);
        okf = okf && (rB[j] == ref);
    }
    // (c) bijectivity + Minv build (c==0 lanes cover all 32 (g,j) positions)
    if ((lane & 15) == 0) {
        const int g = lane >> 4;
        #pragma unroll
        for (int j = 0; j < 8; ++j) {
            atomicAdd(&cnt[rB[j]], 1);
            minv[rB[j]] = 16 * ((j >> 2) & 1) + 4 * g + 2 * ((j >> 1) & 1) + (j & 1);
        }
    }
    __syncthreads();
    if (lane < 32) {
        okf = okf && (cnt[lane] == 1);
        tbl[2048 + lane] = minv[lane];
    }
    const bool allok = __all(okf);
    if (lane == 0) *flag = allok ? 1 : 0;
}

// ---------- build W1/W2/Wo A-fragment tables (after verify tables final) ----------
// W2 columns permuted by Minv so layer-2 B-frag == layer-1 packed D registers.
// Wo frags (frag 48..55): rows replicated (m ignored) -> 3rd-MFMA output rows all
// equal o[n]; columns permuted by the same Minv so packed relu(L2-D) feeds it.
__global__ void build_frags(const float* __restrict__ W1, const float* __restrict__ b1,
                            const float* __restrict__ W2, const float* __restrict__ Wo,
                            const int* __restrict__ tbl,
                            uint4* __restrict__ w1f, uint4* __restrict__ w2f,
                            uint4* __restrict__ w3f) {
    const int t = blockIdx.x * 256 + threadIdx.x;   // 0..3583
    if (t >= 3584) return;
    const int lane = t & 63, frag = t >> 6;
    const float rateB = bf16val(0.025f);
    unsigned u[4] = {0u, 0u, 0u, 0u};
    if (frag < 16) {            // W1: net=frag>>2, mt=frag&3 ; k 0..5 hi, 6..11 lo-residual
        const int net = frag >> 2, mt = frag & 3;
        #pragma unroll
        for (int j = 0; j < 8; ++j) {
            const int s = lane * 8 + j;
            const int m = tbl[s] & 15, k = tbl[512 + s] & 31;
            unsigned bits = 0u;
            if (k < 12) {
                const int kk = (k < 6) ? k : k - 6;
                const int M = net * 64 + 16 * mt + m;
                float v;
                if (kk == 0)                 v = W1[M * 4 + 0];
                else if (kk == 1 || kk == 4) v = W1[M * 4 + 1];
                else if (kk == 2 || kk == 5) v = W1[M * 4 + 2];
                else                         v = W1[M * 4 + 3] + b1[M] / rateB;
                bits = (k < 6) ? bf16u(v) : bf16u(v - bf16val(v));
            }
            u[j >> 1] |= bits << (16 * (j & 1));
        }
        w1f[frag * 64 + lane] = make_uint4(u[0], u[1], u[2], u[3]);
    } else if (frag < 48) {     // W2: f2=frag-16: net=f2>>3, mt=(f2>>1)&3, kc=f2&1
        const int f2 = frag - 16;
        const int net = f2 >> 3, mt = (f2 >> 1) & 3, kc = f2 & 1;
        #pragma unroll
        for (int j = 0; j < 8; ++j) {
            const int s = lane * 8 + j;
            const int m = tbl[s] & 15, k = tbl[512 + s] & 31;
            const float v = W2[(net * 64 + 16 * mt + m) * 64 + 32 * kc + tbl[2048 + k]];
            u[j >> 1] |= bf16u(v) << (16 * (j & 1));
        }
        w2f[f2 * 64 + lane] = make_uint4(u[0], u[1], u[2], u[3]);
    } else {                    // Wo: f3=frag-48: net=f3>>1, kc=f3&1; m-independent
        const int f3 = frag - 48;
        const int net = f3 >> 1, kc = f3 & 1;
        #pragma unroll
        for (int j = 0; j < 8; ++j) {
            const int s = lane * 8 + j;
            const int k = tbl[512 + s] & 31;
            const float v = Wo[net * 64 + 32 * kc + tbl[2048 + k]];
            u[j >> 1] |= bf16u(v) << (16 * (j & 1));
        }
        w3f[f3 * 64 + lane] = make_uint4(u[0], u[1], u[2], u[3]);
    }
}

// ---------- main MFMA path-sim: 4 waves/block, 1 net per wave, LDS-free B1 ----------
// Round-7 structure + MFMA-ized output layer: the Wo-dot epilogue (128 fma/fmax +
// 8-deep shfl chain per net-step) is replaced by perm-packing relu(L2-D) (the
// verified verbatim identity) and 2 MFMAs against replicated-Wo A-frags; each
// lane then reads its own path's o from the nt==q tile -- no cross-lane reduce.
__global__ __launch_bounds__(256, 3)
void sde_mfma_w4(const float* __restrict__ x, const float* __restrict__ z,
                 const float* __restrict__ z1, const float* __restrict__ b2,
                 const float* __restrict__ bo,
                 const int* __restrict__ tbl, const uint4* __restrict__ w1f,
                 const uint4* __restrict__ w2f, const uint4* __restrict__ w3f,
                 const int* __restrict__ flag, float* __restrict__ acc)
{
    if (*flag != 1) return;
    __shared__ __align__(16) float b2_s[256];
    __shared__ float dxch[2][4][64];
    __shared__ float ls_k[NOPTS];
    __shared__ int   maskTab[NSTEPS + 4];

    const int tid = threadIdx.x;
    const int wv = tid >> 6, lane = tid & 63;   // wv == net index
    const int q = lane >> 4, c = lane & 15;

    for (int j = tid; j < 256; j += 256) b2_s[j] = b2[j];
    for (int j = tid; j < NSTEPS + 4; j += 256) maskTab[j] = 0;
    if (tid < NOPTS) ls_k[tid] = x[2 * tid + 1];
    __syncthreads();
    if (tid < NOPTS) atomicOr(&maskTab[(int)x[2 * tid]], 1 << tid);
    __syncthreads();

    // per-lane B1 assembly tables from discovered k-map
    // rows: 0=t 1=S 2=V 3=rate 4=Sres 5=Vres 6=zero
    const unsigned rate16 = bf16u(0.025f);
    unsigned selAB[4], dynM[4], cU[4], mT[4];
    {
        int rowj[8];
        #pragma unroll
        for (int j = 0; j < 8; ++j) {
            const int kb = tbl[1536 + lane * 8 + j] & 31;
            rowj[j] = (kb < 6) ? kb : ((kb < 12) ? kb - 6 : 6);
        }
        #pragma unroll
        for (int w = 0; w < 4; ++w) {
            unsigned s = 0, d = 0, cu = 0, mt_ = 0;
            #pragma unroll
            for (int h = 0; h < 2; ++h) {
                const int r = rowj[2 * w + h];
                unsigned hs = 0x0504u, hd = 0u, hcu = 0u, hmt = 0u;
                if      (r == 1) { hs = 0x0504u; hd = 0xFFFFu; }   // S  = Ap lo16
                else if (r == 2) { hs = 0x0706u; hd = 0xFFFFu; }   // V  = Ap hi16
                else if (r == 4) { hs = 0x0100u; hd = 0xFFFFu; }   // Sr = Bp lo16
                else if (r == 5) { hs = 0x0302u; hd = 0xFFFFu; }   // Vr = Bp hi16
                else if (r == 0) { hmt = 0xFFFFu; }                // t (per-step)
                else if (r == 3) { hcu = rate16; }                 // rate const
                // r==6: zero
                s  |= hs  << (16 * h); d   |= hd  << (16 * h);
                cu |= hcu << (16 * h); mt_ |= hmt << (16 * h);
            }
            selAB[w] = s; dynM[w] = d; cU[w] = cu; mT[w] = mt_;
        }
    }

    const int p_ = blockIdx.x * 64 + lane;      // 64 paths per block
    const float wgt = (p_ < MPATHS) ? 1.0f : 0.0f;
    int pc = (p_ < MPATHS) ? p_ : (MPATHS - 1);
    float sgn = 1.0f; int row_ = pc;
    if (pc >= MC) { sgn = -1.0f; row_ -= MC; }
    const float* __restrict__ zrow  = z  + (size_t)row_ * NSTEPS;
    const float* __restrict__ z1row = z1 + (size_t)row_ * NSTEPS;

    const float hh = 1.0f / 360.0f, sqh = sqrtf(hh);
    const float s75 = 0.86602540378443864676f;
    const float bon = bo[wv];

    // hoisted A fragments for this wave's net, as native 128-bit vectors
    const u32x4* __restrict__ w1v = (const u32x4*)w1f;
    const u32x4* __restrict__ w2v = (const u32x4*)w2f;
    const u32x4* __restrict__ w3v = (const u32x4*)w3f;
    u32x4 a1v[4], a2v[8];
    #pragma unroll
    for (int mt = 0; mt < 4; ++mt) {
        a1v[mt]         = w1v[(wv * 4 + mt) * 64 + lane];
        a2v[2 * mt]     = w2v[((wv * 4 + mt) * 2 + 0) * 64 + lane];
        a2v[2 * mt + 1] = w2v[((wv * 4 + mt) * 2 + 1) * 64 + lane];
    }
    const u32x4 a3v0 = w3v[(wv * 2 + 0) * 64 + lane];
    const u32x4 a3v1 = w3v[(wv * 2 + 1) * 64 + lane];
    // hoisted per-thread-constant L2 bias (C operand)
    float4v c4r[4];
    #pragma unroll
    for (int mt = 0; mt < 4; ++mt)
        c4r[mt] = *(const float4v*)&b2_s[wv * 64 + 16 * mt + 4 * q];

    float S = 100.0f, V = 0.04f;

    // z/z1 chunk state: 4 steps per chunk, prefetch one chunk ahead
    const bool needZ  = (wv == 1) | (wv == 3);
    const bool needZ1 = (wv == 3);
    float4 zc = {0.f, 0.f, 0.f, 0.f}, z1c = {0.f, 0.f, 0.f, 0.f};
    float4 zn = zc, z1n = z1c;
    if (needZ)  zc  = *(const float4*)(zrow);
    if (needZ1) z1c = *(const float4*)(z1row);

    #pragma unroll 1
    for (int ch = 0; ch < NSTEPS / 4; ++ch) {
        // prefetch next chunk (latency hidden under this chunk's 4 steps)
        if (ch + 1 < NSTEPS / 4) {
            if (needZ)  zn  = *(const float4*)(zrow  + 4 * (ch + 1));
            if (needZ1) z1n = *(const float4*)(z1row + 4 * (ch + 1));
        }
        #pragma unroll
        for (int ii = 0; ii < 4; ++ii) {
            const int i = 4 * ch + ii;
            const float zz  = (ii == 0) ? zc.x  : (ii == 1) ? zc.y  : (ii == 2) ? zc.z  : zc.w;
            const float zz1 = (ii == 0) ? z1c.x : (ii == 1) ? z1c.y : (ii == 2) ? z1c.z : z1c.w;
            // per-wave multiplier of this net's output
            float mult;
            if      (wv == 1) mult = sqh * (sgn * zz);
            else if (wv == 3) mult = sqh * (sgn * (-0.5f * zz + s75 * zz1));
            else              mult = hh;

            const float t = (float)i * hh;
            const unsigned tB = bf16u(t);
            const unsigned tB2 = tB | (tB << 16);
            unsigned UW[4];
            #pragma unroll
            for (int w = 0; w < 4; ++w) UW[w] = cU[w] | (mT[w] & tB2);

            // per-lane packed state words (own path)
            const unsigned Shu = bf16u(S), Vhu = bf16u(V);
            const unsigned PA = Shu | (Vhu << 16);
            const float Sr = S - __uint_as_float(Shu << 16);
            const float Vr = V - __uint_as_float(Vhu << 16);
            const unsigned PB = __builtin_amdgcn_perm(__float_as_uint(Vr),
                                                      __float_as_uint(Sr), 0x07060302u);

            float osel = 0.0f;
            #pragma unroll
            for (int nt = 0; nt < 4; ++nt) {
                const int a = (nt << 6) | (c << 2);
                const unsigned Ap = (unsigned)__builtin_amdgcn_ds_bpermute(a, (int)PA);
                const unsigned Bp = (unsigned)__builtin_amdgcn_ds_bpermute(a, (int)PB);
                // B1 built directly in its vector register tuple
                u32x4 b1v;
                b1v.x = (__builtin_amdgcn_perm(Ap, Bp, selAB[0]) & dynM[0]) | UW[0];
                b1v.y = (__builtin_amdgcn_perm(Ap, Bp, selAB[1]) & dynM[1]) | UW[1];
                b1v.z = (__builtin_amdgcn_perm(Ap, Bp, selAB[2]) & dynM[2]) | UW[2];
                b1v.w = (__builtin_amdgcn_perm(Ap, Bp, selAB[3]) & dynM[3]) | UW[3];
                const short8 B1s = __builtin_bit_cast(short8, b1v);

                // ---- layer 1 MFMA -> relu -> pack straight into L2-B tuples ----
                const float4v z4 = {0.f, 0.f, 0.f, 0.f};
                u32x4 bk0, bk1;
                #pragma unroll
                for (int mt = 0; mt < 4; ++mt) {
                    float4v d = mfma16(__builtin_bit_cast(short8, a1v[mt]), B1s, z4);
                    const unsigned r0 = __float_as_uint(fmaxf(d[0], 0.f));
                    const unsigned r1 = __float_as_uint(fmaxf(d[1], 0.f));
                    const unsigned r2 = __float_as_uint(fmaxf(d[2], 0.f));
                    const unsigned r3 = __float_as_uint(fmaxf(d[3], 0.f));
                    const unsigned plo = __builtin_amdgcn_perm(r1, r0, 0x07060302u);
                    const unsigned phi = __builtin_amdgcn_perm(r3, r2, 0x07060302u);
                    if      (mt == 0) { bk0.x = plo; bk0.y = phi; }
                    else if (mt == 1) { bk0.z = plo; bk0.w = phi; }
                    else if (mt == 2) { bk1.x = plo; bk1.y = phi; }
                    else              { bk1.z = plo; bk1.w = phi; }
                }
                const short8 Bk0 = __builtin_bit_cast(short8, bk0);
                const short8 Bk1 = __builtin_bit_cast(short8, bk1);
                // ---- layer 2 MFMA (bias in C) -> relu -> pack into L3-B tuples ----
                u32x4 hk0, hk1;
                #pragma unroll
                for (int mt = 0; mt < 4; ++mt) {
                    float4v d = mfma16(__builtin_bit_cast(short8, a2v[2 * mt]), Bk0, c4r[mt]);
                    d = mfma16(__builtin_bit_cast(short8, a2v[2 * mt + 1]), Bk1, d);
                    const unsigned r0 = __float_as_uint(fmaxf(d[0], 0.f));
                    const unsigned r1 = __float_as_uint(fmaxf(d[1], 0.f));
                    const unsigned r2 = __float_as_uint(fmaxf(d[2], 0.f));
                    const unsigned r3 = __float_as_uint(fmaxf(d[3], 0.f));
                    const unsigned plo = __builtin_amdgcn_perm(r1, r0, 0x07060302u);
                    const unsigned phi = __builtin_amdgcn_perm(r3, r2, 0x07060302u);
                    if      (mt == 0) { hk0.x = plo; hk0.y = phi; }
                    else if (mt == 1) { hk0.z = plo; hk0.w = phi; }
                    else if (mt == 2) { hk1.x = plo; hk1.y = phi; }
                    else              { hk1.z = plo; hk1.w = phi; }
                }
                // ---- output layer MFMA: A = replicated Wo; every row of the
                //      nt tile holds o[16nt+c]; this lane's path lives in nt==q.
                float4v dO = mfma16(__builtin_bit_cast(short8, a3v0),
                                    __builtin_bit_cast(short8, hk0), z4);
                dO = mfma16(__builtin_bit_cast(short8, a3v1),
                            __builtin_bit_cast(short8, hk1), dO);
                if (nt == q) osel = dO[0];
            }
            const float o = osel + bon;

            // exchange: each wave contributes o*mult; dS = w0+w1, dV = w2+w3
            dxch[i & 1][wv][lane] = o * mult;
            __syncthreads();
            const float dS = dxch[i & 1][0][lane] + dxch[i & 1][1][lane];
            const float dV = dxch[i & 1][2][lane] + dxch[i & 1][3][lane];
            S = fmaxf(S + dS, 0.0f);
            V = fmaxf(V + dV, 0.0f);

            if (wv == 0) {
                int mm = maskTab[i + 1];
                while (mm) {
                    const int qq = __ffs(mm) - 1; mm &= mm - 1;
                    float pay = wgt * fmaxf(S - ls_k[qq], 0.0f);
                    #pragma unroll
                    for (int off = 32; off > 0; off >>= 1)
                        pay += __shfl_down(pay, off, 64);
                    if (lane == 0) atomicAdd(&acc[qq], pay);
                }
            }
        }
        zc = zn; z1c = z1n;
    }
}

// ---------- fallback: round-9 dot2 kernel (proven), gated on !flag ----------
__global__ void pack_w(const float* __restrict__ W1, const float* __restrict__ W2,
                       unsigned* __restrict__ wp1, unsigned* __restrict__ wp2) {
    int i = blockIdx.x * 256 + threadIdx.x;
    if (i < 512)              wp1[i] = pkh2(W1[2 * i], W1[2 * i + 1]);
    else if (i < 512 + 8192) { int k = i - 512; wp2[k] = pkh2(W2[2 * k], W2[2 * k + 1]); }
}

__global__ __launch_bounds__(64, 2)
void sde_dot2(const float* __restrict__ x, const float* __restrict__ z,
              const float* __restrict__ z1, const float* __restrict__ b1,
              const float* __restrict__ b2, const float* __restrict__ Wo,
              const float* __restrict__ bo, const uint4* __restrict__ wp1,
              const uint4* __restrict__ wp2, const int* __restrict__ flag,
              float* __restrict__ acc)
{
    if (*flag == 1) return;
    __shared__ __align__(16) uint4 wlds[2176];
    __shared__ float ls_k[NOPTS];
    __shared__ int   maskTab[NSTEPS + 4];
    const int tid = threadIdx.x;
    for (int j = tid; j < 2176; j += 64) wlds[j] = (j < 128) ? wp1[j] : wp2[j - 128];
    for (int jj = tid; jj < NSTEPS + 4; jj += 64) maskTab[jj] = 0;
    if (tid < NOPTS) ls_k[tid] = x[2 * tid + 1];
    __syncthreads();
    if (tid < NOPTS) atomicOr(&maskTab[(int)x[2 * tid]], 1 << tid);
    __syncthreads();
    const int pA = blockIdx.x * 128 + tid, pB = pA + 64;
    const float wgtA = (pA < MPATHS) ? 1.0f : 0.0f;
    const float wgtB = (pB < MPATHS) ? 1.0f : 0.0f;
    int pcA = (pA < MPATHS) ? pA : (MPATHS - 1);
    int pcB = (pB < MPATHS) ? pB : (MPATHS - 1);
    float sgnA = 1.0f, sgnB = 1.0f; int rowA = pcA, rowB = pcB;
    if (pcA >= MC) { sgnA = -1.0f; rowA -= MC; }
    if (pcB >= MC) { sgnB = -1.0f; rowB -= MC; }
    const float* __restrict__ zA  = z  + (size_t)rowA * NSTEPS;
    const float* __restrict__ z1A = z1 + (size_t)rowA * NSTEPS;
    const float* __restrict__ zB  = z  + (size_t)rowB * NSTEPS;
    const float* __restrict__ z1B = z1 + (size_t)rowB * NSTEPS;
    const float hh = 1.0f / 360.0f, sqh = sqrtf(hh);
    const float s75 = 0.86602540378443864676f, rate = 0.025f;
    float SA = 100.0f, VA = 0.04f, SB = 100.0f, VB = 0.04f;
    #pragma unroll 1
    for (int i = 0; i < NSTEPS; ++i) {
        const float zcrA = zA[i], z1rA = z1A[i], zcrB = zB[i], z1rB = z1B[i];
        const float dWA = sqh * (sgnA * zcrA);
        const float dW1A = sqh * (sgnA * (-0.5f * zcrA + s75 * z1rA));
        const float dWB = sqh * (sgnB * zcrB);
        const float dW1B = sqh * (sgnB * (-0.5f * zcrB + s75 * z1rB));
        const float t = (float)i * hh;
        const unsigned inA01 = pkrtz(t, SA), inA23 = pkrtz(VA, rate);
        const unsigned inB01 = pkrtz(t, SB), inB23 = pkrtz(VB, rate);
        float dSA = 0.f, dVA = 0.f, dSB = 0.f, dVB = 0.f;
        #pragma unroll 1
        for (int net = 0; net < 4; ++net) {
            const float* __restrict__ b1n = b1 + net * 64;
            const float* __restrict__ b2n = b2 + net * 64;
            const float* __restrict__ won = Wo + net * 64;
            const uint4* __restrict__ wl1 = &wlds[net * 32];
            const uint4* __restrict__ wl2 = &wlds[128 + net * 512];
            u32x32 hA, hB;
            #pragma unroll
            for (int u = 0; u < 64; u += 2) {
                const uint4 wv = wl1[u >> 1];
                const float bb0 = b1n[u], bb1 = b1n[u + 1];
                float a0 = fdot2(wv.x, inA01, bb0); a0 = fdot2(wv.y, inA23, a0);
                float a1 = fdot2(wv.z, inA01, bb1); a1 = fdot2(wv.w, inA23, a1);
                float c0 = fdot2(wv.x, inB01, bb0); c0 = fdot2(wv.y, inB23, c0);
                float c1 = fdot2(wv.z, inB01, bb1); c1 = fdot2(wv.w, inB23, c1);
                hA[u >> 1] = pkrtz(fmaxf(a0, 0.f), fmaxf(a1, 0.f));
                hB[u >> 1] = pkrtz(fmaxf(c0, 0.f), fmaxf(c1, 0.f));
            }
            float outA = bo[net], outB = outA;
            #pragma unroll 1
            for (int j = 0; j < 64; j += 4) {
                const uint4* __restrict__ r0 = wl2 + (j + 0) * 8;
                const uint4* __restrict__ r1 = wl2 + (j + 1) * 8;
                const uint4* __restrict__ r2 = wl2 + (j + 2) * 8;
                const uint4* __restrict__ r3 = wl2 + (j + 3) * 8;
                float a0 = b2n[j], a1 = b2n[j + 1], a2 = b2n[j + 2], a3 = b2n[j + 3];
                float c0 = a0, c1 = a1, c2 = a2, c3 = a3;
                #pragma unroll
                for (int kk = 0; kk < 8; ++kk) {
                    const uint4 w0 = r0[kk], w1 = r1[kk], w2 = r2[kk], w3 = r3[kk];
                    const unsigned hA0 = hA[4 * kk], hA1 = hA[4 * kk + 1];
                    const unsigned hA2 = hA[4 * kk + 2], hA3 = hA[4 * kk + 3];
                    const unsigned hB0 = hB[4 * kk], hB1 = hB[4 * kk + 1];
                    const unsigned hB2 = hB[4 * kk + 2], hB3 = hB[4 * kk + 3];
                    a0 = fdot2(w0.x, hA0, a0); a0 = fdot2(w0.y, hA1, a0);
                    a0 = fdot2(w0.z, hA2, a0); a0 = fdot2(w0.w, hA3, a0);
                    a1 = fdot2(w1.x, hA0, a1); a1 = fdot2(w1.y, hA1, a1);
                    a1 = fdot2(w1.z, hA2, a1); a1 = fdot2(w1.w, hA3, a1);
                    a2 = fdot2(w2.x, hA0, a2); a2 = fdot2(w2.y, hA1, a2);
                    a2 = fdot2(w2.z, hA2, a2); a2 = fdot2(w2.w, hA3, a2);
                    a3 = fdot2(w3.x, hA0, a3); a3 = fdot2(w3.y, hA1, a3);
                    a3 = fdot2(w3.z, hA2, a3); a3 = fdot2(w3.w, hA3, a3);
                    c0 = fdot2(w0.x, hB0, c0); c0 = fdot2(w0.y, hB1, c0);
                    c0 = fdot2(w0.z, hB2, c0); c0 = fdot2(w0.w, hB3, c0);
                    c1 = fdot2(w1.x, hB0, c1); c1 = fdot2(w1.y, hB1, c1);
                    c1 = fdot2(w1.z, hB2, c1); c1 = fdot2(w1.w, hB3, c1);
                    c2 = fdot2(w2.x, hB0, c2); c2 = fdot2(w2.y, hB1, c2);
                    c2 = fdot2(w2.z, hB2, c2); c2 = fdot2(w2.w, hB3, c2);
                    c3 = fdot2(w3.x, hB0, c3); c3 = fdot2(w3.y, hB1, c3);
                    c3 = fdot2(w3.z, hB2, c3); c3 = fdot2(w3.w, hB3, c3);
                }
                const float wo0 = won[j], wo1 = won[j + 1];
                const float wo2 = won[j + 2], wo3 = won[j + 3];
                outA = fmaf(wo0, fmaxf(a0, 0.f), outA); outA = fmaf(wo1, fmaxf(a1, 0.f), outA);
                outA = fmaf(wo2, fmaxf(a2, 0.f), outA); outA = fmaf(wo3, fmaxf(a3, 0.f), outA);
                outB = fmaf(wo0, fmaxf(c0, 0.f), outB); outB = fmaf(wo1, fmaxf(c1, 0.f), outB);
                outB = fmaf(wo2, fmaxf(c2, 0.f), outB); outB = fmaf(wo3, fmaxf(c3, 0.f), outB);
            }
            const float msA = (net == 0) ? hh : (net == 1) ? dWA  : 0.0f;
            const float mvA = (net == 2) ? hh : (net == 3) ? dW1A : 0.0f;
            const float msB = (net == 0) ? hh : (net == 1) ? dWB  : 0.0f;
            const float mvB = (net == 2) ? hh : (net == 3) ? dW1B : 0.0f;
            dSA = fmaf(outA, msA, dSA); dVA = fmaf(outA, mvA, dVA);
            dSB = fmaf(outB, msB, dSB); dVB = fmaf(outB, mvB, dVB);
        }
        SA = fmaxf(SA + dSA, 0.f); VA = fmaxf(VA + dVA, 0.f);
        SB = fmaxf(SB + dSB, 0.f); VB = fmaxf(VB + dVB, 0.f);
        int mm = maskTab[i + 1];
        while (mm) {
            const int qq = __ffs(mm) - 1; mm &= mm - 1;
            float pay = wgtA * fmaxf(SA - ls_k[qq], 0.f) + wgtB * fmaxf(SB - ls_k[qq], 0.f);
            #pragma unroll
            for (int off = 32; off > 0; off >>= 1)
                pay += __shfl_down(pay, off, 64);
            if (tid == 0) atomicAdd(&acc[qq], pay);
        }
    }
}

__global__ void price_kernel(const float* __restrict__ x, const float* __restrict__ acc,
                             float* __restrict__ out) {
    const int q = threadIdx.x;
    if (q < NOPTS) {
        const float mat = x[q * 2];
        out[q] = acc[q] * (1.0f / (float)MPATHS) * expf((-0.025f * mat) / 360.0f);
    }
}

extern "C" void kernel_launch(void* const* d_in, const int* in_sizes, int n_in,
                              void* d_out, int out_size, void* d_ws, size_t ws_size,
                              hipStream_t stream)
{
    const float* x  = (const float*)d_in[0];
    const float* z  = (const float*)d_in[1];
    const float* z1 = (const float*)d_in[2];
    const float* W1 = (const float*)d_in[3];
    const float* b1 = (const float*)d_in[4];
    const float* W2 = (const float*)d_in[5];
    const float* b2 = (const float*)d_in[6];
    const float* Wo = (const float*)d_in[7];
    const float* bo = (const float*)d_in[8];

    char* ws = (char*)d_ws;
    float*    acc  = (float*)ws;                 // 128 B
    int*      flag = (int*)(ws + 256);
    int*      tbl  = (int*)(ws + 1024);          // 8.3 KB tables (incl. Minv)
    uint4*    w1f  = (uint4*)(ws + 16384);       // 16 KB
    uint4*    w2f  = (uint4*)(ws + 32768);       // 32 KB
    unsigned* wp1  = (unsigned*)(ws + 65536);    // 2 KB
    unsigned* wp2  = wp1 + 512;                  // 32 KB (ends at 100352)
    uint4*    w3f  = (uint4*)(ws + 100352);      // 512 B (Wo replicated frags)

    (void)hipMemsetAsync(acc, 0, NOPTS * sizeof(float), stream);
    pack_w<<<(512 + 8192 + 255) / 256, 256, 0, stream>>>(W1, W2, wp1, wp2);
    probe_mn<<<1, 64, 0, stream>>>(tbl);
    probe_k<<<512, 64, 0, stream>>>(tbl);
    finalize_verify<<<1, 64, 0, stream>>>(tbl, flag);
    build_frags<<<14, 256, 0, stream>>>(W1, b1, W2, Wo, tbl, w1f, w2f, w3f);

    const int gridS = (MPATHS + 63) / 64;    // 1563 blocks x 4 waves (net-per-wave)
    sde_mfma_w4<<<gridS, 256, 0, stream>>>(x, z, z1, b2, bo, tbl, w1f, w2f, w3f,
                                           flag, acc);
    const int gridF = (MPATHS + 127) / 128;  // 782 (fallback)
    sde_dot2<<<gridF, 64, 0, stream>>>(x, z, z1, b1, b2, Wo, bo,
                                       (const uint4*)wp1, (const uint4*)wp2, flag, acc);
    price_kernel<<<1, 64, 0, stream>>>(x, acc, (float*)d_out);
}